// Round 13
// baseline (2829.182 us; speedup 1.0000x reference)
//
#include <hip/hip_runtime.h>

// Deep Kalman Filter inference, MI355X/gfx950.
// pack_all, scan_pipe (64 WG x 512 thr: 16 rnn + 16 zscan + 32 throttled
// xw producers, chunked one-way flag sync), dpar (2048 WG), finalize.
// R12 A/B lesson: 4-wave scan (1 wave/SIMD) = 3.2us/step, 8-wave
// (2/SIMD) = 2.5us/step -- latency hiding beats reduced LDS-broadcast
// redundancy. Scan roles here are the R5/R6 512-thread bodies + flags.
// R9: concurrent bulk kills the scan; R10: dpar needs occupancy ->
// separate. R11: keep staged m_st epilogue (store coalescing).
// R2: coarse one-way sync. R3: on-chip weight budget. R4/R5: pin via asm.
// R8: arch "v" regs cap at 256.

#define T_LEN 512
#define BATCH 256
#define DIMX  128
#define ZDIM  128
#define RHD   512
#define CHUNK 32

typedef _Float16 f16;
typedef _Float16 f16x4 __attribute__((ext_vector_type(4)));
typedef _Float16 f16x8 __attribute__((ext_vector_type(8)));
typedef float    f32x4 __attribute__((ext_vector_type(4)));

#define MFMA16(a,b,c) __builtin_amdgcn_mfma_f32_16x16x32_f16((a),(b),(c),0,0,0)

// ---- packed weight element offsets (f16 elements) ----
#define PK_WIH  0u
#define PK_WHH  65536u
#define PK_G1   327680u
#define PK_G2   360448u
#define PK_P1   393216u
#define PK_P2   425984u
#define PK_TMU  458752u
#define PK_TLV  475136u
#define PK_CBH  491520u
#define PK_CBML 557056u
#define PK_E1   688128u
#define PK_E2   720896u
#define PK_EMU  786432u

// ---- workspace byte offsets ----
#define WS_XW   0ull                          // f16 [T][B][RH]: xw in, h out (aliased)
#define WS_Z    (WS_XW  + 134217728ull)       // f16 [T+1][B][Z]
#define WS_MU   (WS_Z   + 33619968ull)        // f16 [T][B][Z]
#define WS_LV   (WS_MU  + 33554432ull)        // f16 [T][B][Z]
#define WS_PK   (WS_LV  + 33554432ull)        // f16 packed weights
#define WS_PART (WS_PK  + 1638400ull)         // f32 [2048][2]
#define WS_PROG (WS_PART + 16384ull)          // u32: prog[16], xcnt[16] @ +32
#define WS_END  (WS_PROG + 256ull)

// =====================================================================
// helpers
// =====================================================================
__device__ __forceinline__ void ldsfence() {
  asm volatile("s_waitcnt lgkmcnt(0)" ::: "memory");
  __builtin_amdgcn_sched_barrier(0);
}

// lgkm-only workgroup barrier (global ops stay in flight).
__device__ __forceinline__ void lbar() {
  asm volatile("s_waitcnt lgkmcnt(0)" ::: "memory");
  __builtin_amdgcn_s_barrier();
  asm volatile("" ::: "memory");
}

// Anti-rematerialization pin.
__device__ __forceinline__ void pin8(f16x8& v) {
  f32x4 t = __builtin_bit_cast(f32x4, v);
  asm volatile("" : "+v"(t));
  v = __builtin_bit_cast(f16x8, t);
}

template<int N>
__device__ __forceinline__ void zacc(f32x4* a) {
  f32x4 z = {0.f, 0.f, 0.f, 0.f};
#pragma unroll
  for (int i = 0; i < N; ++i) a[i] = z;
}

__device__ __forceinline__ f16x8 cvt8(const float* p) {
  float4 a = *(const float4*)p, b = *(const float4*)(p + 4);
  f16x8 r;
  r[0] = (f16)a.x; r[1] = (f16)a.y; r[2] = (f16)a.z; r[3] = (f16)a.w;
  r[4] = (f16)b.x; r[5] = (f16)b.y; r[6] = (f16)b.z; r[7] = (f16)b.w;
  return r;
}

// XOR swizzle: 16B-chunk of row r at f16-col c -> c ^ ((r&7)<<3)
__device__ __forceinline__ int swz(int row, int col) {
  return (row << 9) + (col ^ ((row & 7) << 3));     // stride 512 f16
}
__device__ __forceinline__ int swz128(int row, int col) {
  return (row << 7) + (col ^ ((row & 7) << 3));     // stride 128 f16
}

// (dpar helpers)
template<int KS>
__device__ __forceinline__ void load_af(const f16* src, int sstr, int lane, f16x8* af) {
#pragma unroll
  for (int ks = 0; ks < KS; ++ks)
    af[ks] = *(const f16x8*)(src + (lane & 15) * sstr + ks * 32 + ((lane >> 4) << 3));
}

template<int KS, int NT>
__device__ __forceinline__ void gemm_regA(const f16x8* af, const f16* __restrict__ bp,
                                          int lane, f32x4* acc) {
#pragma unroll
  for (int ks = 0; ks < KS; ++ks)
#pragma unroll
    for (int j = 0; j < NT; ++j) {
      f16x8 bf = *(const f16x8*)(bp + (((size_t)(ks * NT + j)) << 9) + (lane << 3));
      acc[j] = MFMA16(af[ks], bf, acc[j]);
    }
}

template<int NT>
__device__ __forceinline__ void store_relu(const f32x4* acc, const float* __restrict__ bias,
                                           f16* dst, int dstr, int lane) {
  int colv = lane & 15, rb = (lane >> 4) << 2;
#pragma unroll
  for (int j = 0; j < NT; ++j)
#pragma unroll
    for (int r = 0; r < 4; ++r)
      dst[(rb + r) * dstr + j * 16 + colv] = (f16)fmaxf(acc[j][r] + bias[j * 16 + colv], 0.f);
}

__device__ __forceinline__ unsigned ldflag(const unsigned* p) {
  return __hip_atomic_load(p, __ATOMIC_RELAXED, __HIP_MEMORY_SCOPE_AGENT);
}

// =====================================================================
// pack_all: all 13 matrices. W[K][N] fp32 -> fp16 frags (fi = ks*(N/16)+nt)
// =====================================================================
struct PackEnt { const float* s1; const float* s2; int nsplit, K, N; unsigned dst, wg0; };
struct PackTab { PackEnt e[13]; };

__global__ void pack_all_kernel(PackTab tb, f16* __restrict__ pk) {
  int i = 0;
#pragma unroll
  for (int k = 1; k < 13; ++k)
    if (blockIdx.x >= tb.e[k].wg0) i = k;
  const PackEnt& E = tb.e[i];
  int idx = (blockIdx.x - E.wg0) * 256 + threadIdx.x;
  if (idx >= E.K * E.N) return;
  int j = idx & 7, l = (idx >> 3) & 63, fi = idx >> 9;
  int NTt = E.N >> 4;
  int nt = fi % NTt, ks = fi / NTt;
  int k = ks * 32 + ((l >> 4) << 3) + j;
  int n = (nt << 4) + (l & 15);
  float v;
  if (n < E.nsplit) v = E.s1[(size_t)k * E.nsplit + n];
  else              v = E.s2[(size_t)k * (E.N - E.nsplit) + (n - E.nsplit)];
  pk[E.dst + idx] = (f16)v;
}

__global__ void zero_prog_kernel(unsigned* __restrict__ p) {
  if (threadIdx.x < 64)
    __hip_atomic_store(p + threadIdx.x, 0u, __ATOMIC_RELAXED, __HIP_MEMORY_SCOPE_AGENT);
}

// =====================================================================
// scan_pipe: 64 WGs x 512 thr (8 waves, 2/SIMD; 1 WG/CU via LDS).
// WG 0..15:  rnn role (R5 body): Whh ks0..11 regs (192v), ks12..15 LDS.
// WG 16..31: zscan role (R6 body): cbh regs, cbml ks0..11 regs + 64KB LDS.
// WG 32..63: xw producers (8 wave-tiles/pass), <=3 chunks ahead of rnn.
// =====================================================================
__global__ __launch_bounds__(512, 2) void scan_pipe_kernel(
    const f16* __restrict__ pk, const float* __restrict__ h0,
    const float* __restrict__ zq0, const float* __restrict__ chb,
    const float* __restrict__ cmb, const float* __restrict__ clb,
    const float* __restrict__ eps_comb, f16* __restrict__ xw,
    f16* __restrict__ z_all, f16* __restrict__ mu_all, f16* __restrict__ lv_all,
    const float* __restrict__ x, const float* __restrict__ bih,
    const float* __restrict__ bhh, unsigned* __restrict__ flags) {
  __shared__ __align__(16) f16 lds[73728];  // 144 KB union
  const int tid = threadIdx.x, lane = tid & 63, w = tid >> 6;
  const int colv = lane & 15, l4 = lane >> 4;
  unsigned* prog = flags;        // rnn chunk progress [16]
  unsigned* xcnt = flags + 32;   // xw block-tiles done per chunk [16]

  if (blockIdx.x < 16) {
    // ------------------- RNN role (8 waves, R5 body) -------------------
    const int g = blockIdx.x, b0 = g * 16;
    f16* whh_lds = lds;          // 65536 f16 (ks 12..15)
    f16* h_st = lds + 65536;     // 8192 f16, swizzled [16][512]
    {
      const uint4* src = (const uint4*)(pk + PK_WHH + 196608u);
      for (int i = tid; i < 8192; i += 512) ((uint4*)whh_lds)[i] = src[i];
    }
    f16x8 whhA[4][12];
#pragma unroll
    for (int mt = 0; mt < 4; ++mt)
#pragma unroll
      for (int ks = 0; ks < 12; ++ks) {
        whhA[mt][ks] = *(const f16x8*)(pk + PK_WHH +
            ((size_t)(ks * 32 + 4 * w + mt) << 9) + (lane << 3));
        pin8(whhA[mt][ks]);
      }
    for (int i = tid; i < 8192; i += 512) h_st[swz(i >> 9, i & 511)] = (f16)h0[i & 511];
    __syncthreads();

    // wait for xw chunk 0 before the initial xwc load
    if (tid == 0) { while (ldflag(xcnt + 0) < 64u) __builtin_amdgcn_s_sleep(2); }
    __syncthreads();
    __builtin_amdgcn_fence(__ATOMIC_ACQUIRE, "agent");

    const int off0 = (4 * w) * 16 + l4 * 4;
    f16* xp = xw + (size_t)(b0 + colv) * RHD;
    f16x4 xwc[4], xwn[4];
#pragma unroll
    for (int mt = 0; mt < 4; ++mt) xwc[mt] = *(const f16x4*)(xp + off0 + mt * 16);

    for (int c = 0; c < T_LEN / CHUNK; ++c) {
      // ensure xw chunk c+1 (read by the boundary prefetch) is written
      const int cw = (c + 1 < T_LEN / CHUNK) ? c + 1 : T_LEN / CHUNK - 1;
      if (tid == 0) { while (ldflag(xcnt + cw) < 64u) __builtin_amdgcn_s_sleep(2); }
      __syncthreads();
      __builtin_amdgcn_fence(__ATOMIC_ACQUIRE, "agent");
#pragma unroll 1
      for (int tt = 0; tt < CHUNK; ++tt) {
        int t = c * CHUNK + tt;
        f16* xpn = (t < T_LEN - 1) ? xp + (size_t)BATCH * RHD : xp;
#pragma unroll
        for (int mt = 0; mt < 4; ++mt) xwn[mt] = *(const f16x4*)(xpn + off0 + mt * 16);

        f32x4 acc[4]; zacc<4>(acc);
#pragma unroll
        for (int kc = 0; kc < 6; ++kc) {
          f16x8 B2[2];
#pragma unroll
          for (int kk = 0; kk < 2; ++kk)
            B2[kk] = *(const f16x8*)&h_st[swz(colv, (kc * 2 + kk) * 32 + l4 * 8)];
#pragma unroll
          for (int kk = 0; kk < 2; ++kk)
#pragma unroll
            for (int mt = 0; mt < 4; ++mt)
              acc[mt] = MFMA16(whhA[mt][kc * 2 + kk], B2[kk], acc[mt]);
        }
#pragma unroll
        for (int kc = 0; kc < 2; ++kc) {
          f16x8 B2[2];
#pragma unroll
          for (int kk = 0; kk < 2; ++kk)
            B2[kk] = *(const f16x8*)&h_st[swz(colv, (12 + kc * 2 + kk) * 32 + l4 * 8)];
#pragma unroll
          for (int kk = 0; kk < 2; ++kk)
#pragma unroll
            for (int mt = 0; mt < 4; ++mt)
              acc[mt] = MFMA16(*(const f16x8*)(whh_lds +
                  ((((kc * 2 + kk) * 32 + 4 * w + mt) << 6) + lane) * 8), B2[kk], acc[mt]);
        }
        lbar();  // B1: h_st reads done
#pragma unroll
        for (int mt = 0; mt < 4; ++mt) {
          f16x4 h4;
#pragma unroll
          for (int r = 0; r < 4; ++r)
            h4[r] = (f16)fmaxf(acc[mt][r] + (float)xwc[mt][r], 0.f);
          *(f16x4*)&h_st[swz(colv, off0 + mt * 16)] = h4;
          *(f16x4*)(xp + off0 + mt * 16) = h4;  // h overwrites xw[t]
        }
        lbar();  // B2
        xp = xpn;
#pragma unroll
        for (int mt = 0; mt < 4; ++mt) xwc[mt] = xwn[mt];
      }
      __syncthreads();  // drains all waves' vmem (h stores at L2)
      if (tid == 0)
        __hip_atomic_store(prog + g, (unsigned)(c + 1), __ATOMIC_RELEASE,
                           __HIP_MEMORY_SCOPE_AGENT);
    }
  } else if (blockIdx.x < 32) {
    // ------------------- zscan role (8 waves, R6 body) -------------------
    const int g = blockIdx.x - 16, b0 = g * 16;
    f16* cbml_lds = lds;           // 32768 f16 (ks 12..15)
    f16* hc_st = lds + 32768;      // 8192 f16, swizzled [16][512]
    f16* z_st  = lds + 40960;      // 2048 f16, swizzled [16][128]
    f16* m_st  = lds + 43008;      // [16][264] f16
    {
      const uint4* src = (const uint4*)(pk + PK_CBML + 98304u);
      for (int i = tid; i < 4096; i += 512) ((uint4*)cbml_lds)[i] = src[i];
    }
    f16x8 cbhA[4][4];
#pragma unroll
    for (int mt = 0; mt < 4; ++mt)
#pragma unroll
      for (int ks = 0; ks < 4; ++ks) {
        cbhA[mt][ks] = *(const f16x8*)(pk + PK_CBH +
            ((size_t)(ks * 32 + 4 * w + mt) << 9) + (lane << 3));
        pin8(cbhA[mt][ks]);
      }
    f16x8 cbmlA[2][12];
#pragma unroll
    for (int mt = 0; mt < 2; ++mt)
#pragma unroll
      for (int ks = 0; ks < 12; ++ks) {
        cbmlA[mt][ks] = *(const f16x8*)(pk + PK_CBML +
            ((size_t)(ks * 16 + 2 * w + mt) << 9) + (lane << 3));
        pin8(cbmlA[mt][ks]);
      }
    f16x4 chbv[4];
#pragma unroll
    for (int mt = 0; mt < 4; ++mt)
#pragma unroll
      for (int r = 0; r < 4; ++r)
        chbv[mt][r] = (f16)chb[(4 * w + mt) * 16 + l4 * 4 + r];
    float mb[2][4];
#pragma unroll
    for (int mt = 0; mt < 2; ++mt)
#pragma unroll
      for (int r = 0; r < 4; ++r) {
        int d = (2 * w + mt) * 16 + l4 * 4 + r;
        mb[mt][r] = (d < 128) ? cmb[d] : clb[d - 128];
      }
    for (int i = tid; i < 2048; i += 512) {
      f16 zv = (f16)zq0[i & 127];
      z_st[swz128(i >> 7, i & 127)] = zv;
      z_all[(size_t)(b0 + (i >> 7)) * ZDIM + (i & 127)] = zv;  // z_all[0]
    }
    __syncthreads();

    const int hoff = (4 * w) * 16 + l4 * 4;
    const int be = tid >> 5, d0 = (tid & 31) * 4;
    const f16* hp = xw + (size_t)(b0 + colv) * RHD;
    const float* epb = eps_comb + (size_t)(b0 + be) * ZDIM + d0;
    f16x4 hvc[4], hvn[4];

    for (int c = 0; c < T_LEN / CHUNK; ++c) {
      if (tid == 0) {
        while (ldflag(prog + g) < (unsigned)(c + 1)) __builtin_amdgcn_s_sleep(2);
      }
      __syncthreads();
      __builtin_amdgcn_fence(__ATOMIC_ACQUIRE, "agent");
      {
        const f16* hpt = hp + (size_t)(c * CHUNK) * BATCH * RHD;
#pragma unroll
        for (int mt = 0; mt < 4; ++mt) hvc[mt] = *(const f16x4*)(hpt + hoff + mt * 16);
      }
#pragma unroll 1
      for (int tt = 0; tt < CHUNK; ++tt) {
        int t = c * CHUNK + tt;
        float4 ep = *(const float4*)(epb + (size_t)t * BATCH * ZDIM);

        // GEMM1: cbh @ z (M=512, K=128)
        f16x8 zB[4];
#pragma unroll
        for (int ks = 0; ks < 4; ++ks)
          zB[ks] = *(const f16x8*)&z_st[swz128(colv, ks * 32 + l4 * 8)];
        f32x4 a1[4]; zacc<4>(a1);
#pragma unroll
        for (int ks = 0; ks < 4; ++ks)
#pragma unroll
          for (int mt = 0; mt < 4; ++mt)
            a1[mt] = MFMA16(cbhA[mt][ks], zB[ks], a1[mt]);
        // epi1: hc = 0.5*(tanh(a1+chb) + h)
#pragma unroll
        for (int mt = 0; mt < 4; ++mt) {
          f16x4 hc4;
#pragma unroll
          for (int r = 0; r < 4; ++r) {
            float cs = a1[mt][r] + (float)chbv[mt][r];
            float ex = __builtin_amdgcn_exp2f(cs * 2.885390082f);   // e^(2x)
            float th = 1.f - 2.f * __builtin_amdgcn_rcpf(ex + 1.f); // tanh
            hc4[r] = (f16)(0.5f * (th + (float)hvc[mt][r]));
          }
          *(f16x4*)&hc_st[swz(colv, hoff + mt * 16)] = hc4;
        }
        lbar();  // B1: hc ready (and z_st reads done)
        // prefetch next-step h (within chunk only; overlaps GEMM2)
        if (tt < CHUNK - 1) {
          const f16* hpt = hp + (size_t)(t + 1) * BATCH * RHD;
#pragma unroll
          for (int mt = 0; mt < 4; ++mt) hvn[mt] = *(const f16x4*)(hpt + hoff + mt * 16);
        }
        // GEMM2: cbml @ hc (M=256, K=512); ks 0..11 reg A, 12..15 LDS A
        f32x4 a2[2]; zacc<2>(a2);
#pragma unroll
        for (int kc = 0; kc < 6; ++kc) {
          f16x8 hcB[2];
#pragma unroll
          for (int kk = 0; kk < 2; ++kk)
            hcB[kk] = *(const f16x8*)&hc_st[swz(colv, (kc * 2 + kk) * 32 + l4 * 8)];
#pragma unroll
          for (int kk = 0; kk < 2; ++kk)
#pragma unroll
            for (int mt = 0; mt < 2; ++mt)
              a2[mt] = MFMA16(cbmlA[mt][kc * 2 + kk], hcB[kk], a2[mt]);
        }
#pragma unroll
        for (int kc = 0; kc < 2; ++kc) {
          f16x8 hcB[2];
#pragma unroll
          for (int kk = 0; kk < 2; ++kk)
            hcB[kk] = *(const f16x8*)&hc_st[swz(colv, (12 + kc * 2 + kk) * 32 + l4 * 8)];
#pragma unroll
          for (int kk = 0; kk < 2; ++kk)
#pragma unroll
            for (int mt = 0; mt < 2; ++mt)
              a2[mt] = MFMA16(*(const f16x8*)(cbml_lds +
                  ((((kc * 2 + kk) * 16 + 2 * w + mt) << 6) + lane) * 8), hcB[kk], a2[mt]);
        }
#pragma unroll
        for (int mt = 0; mt < 2; ++mt) {
          f16x4 v;
#pragma unroll
          for (int r = 0; r < 4; ++r) v[r] = (f16)(a2[mt][r] + mb[mt][r]);  // biased
          *(f16x4*)&m_st[colv * 264 + (2 * w + mt) * 16 + l4 * 4] = v;
        }
        lbar();  // B2: mu|lv ready
        // z epilogue: thread -> (batch be, dims d0..d0+3); m_st biased
        {
          f16x4 muf = *(const f16x4*)&m_st[be * 264 + d0];
          f16x4 lvf = *(const f16x4*)&m_st[be * 264 + 128 + d0];
          float epv[4] = {ep.x, ep.y, ep.z, ep.w};
          f16x4 z4;
#pragma unroll
          for (int r = 0; r < 4; ++r) {
            float mu = (float)muf[r], lv = (float)lvf[r];
            z4[r] = (f16)(mu + epv[r] * __builtin_amdgcn_exp2f(lv * 0.7213475204f));
          }
          *(f16x4*)&z_st[swz128(be, d0)] = z4;
          size_t o = ((size_t)t * BATCH + b0 + be) * ZDIM + d0;
          *(f16x4*)(z_all + o + (size_t)BATCH * ZDIM) = z4;  // slot t+1
          *(f16x4*)(mu_all + o) = muf;
          *(f16x4*)(lv_all + o) = lvf;
        }
        lbar();  // B3: z_st/m_st safe for next step
#pragma unroll
        for (int mt = 0; mt < 4; ++mt) hvc[mt] = hvn[mt];
      }
    }
  } else {
    // -------- xw producer role (32 blocks x 8 waves, throttled) --------
    const int p = blockIdx.x - 32;
    float* bs = (float*)lds;  // [512]
    for (int i = tid; i < 512; i += 512) bs[i] = bih[i] + bhh[i];
    if (tid < 512) { int i2 = tid; bs[i2] = bih[i2] + bhh[i2]; }
    __syncthreads();
    for (int c = 0; c < T_LEN / CHUNK; ++c) {
      if (c > 2) {  // stay <= 3 chunks ahead of the slowest rnn group
        if (tid == 0) {
          for (;;) {
            unsigned mn = 0xffffffffu;
            for (int g2 = 0; g2 < 16; ++g2) mn = min(mn, ldflag(prog + g2));
            if (mn >= (unsigned)(c - 2)) break;
            __builtin_amdgcn_s_sleep(32);
          }
        }
        __syncthreads();
      }
#pragma unroll 1
      for (int q = 0; q < 2; ++q) {
        const int i = c * 64 + p * 2 + q;    // block-tile: 128 (t,b)-rows
        const int m0 = i * 128 + w * 16;
        const int t = m0 >> 8, b0 = m0 & 255;
        f16x8 xB[4];
        const float* xr = x + ((size_t)(b0 + colv) * T_LEN + t) * DIMX;
#pragma unroll
        for (int ks = 0; ks < 4; ++ks) xB[ks] = cvt8(xr + ks * 32 + l4 * 8);
        f32x4 acc[32]; zacc<32>(acc);
#pragma unroll
        for (int ks = 0; ks < 4; ++ks)
#pragma unroll
          for (int mt = 0; mt < 32; ++mt)
            acc[mt] = MFMA16(*(const f16x8*)(pk + PK_WIH +
                ((size_t)(ks * 32 + mt) << 9) + (lane << 3)), xB[ks], acc[mt]);
        f16* xo = xw + ((size_t)t * BATCH + b0 + colv) * RHD;
#pragma unroll
        for (int mt = 0; mt < 32; ++mt) {
          f16x4 v;
#pragma unroll
          for (int r = 0; r < 4; ++r) v[r] = (f16)(acc[mt][r] + bs[mt * 16 + l4 * 4 + r]);
          *(f16x4*)(xo + mt * 16 + l4 * 4) = v;
        }
        __syncthreads();  // all waves' stores drained (vmcnt0 at barrier)
        if (tid == 0)
          __hip_atomic_fetch_add(xcnt + c, 1u, __ATOMIC_RELEASE,
                                 __HIP_MEMORY_SCOPE_AGENT);
      }
    }
  }
}

// =====================================================================
// Phase D: parallel transition/emitter/losses over all (t,b). (R8 form)
// =====================================================================
__global__ __launch_bounds__(256) void dpar_kernel(
    const f16* __restrict__ z_all, const f16* __restrict__ mu_all,
    const f16* __restrict__ lv_all, const float* __restrict__ y,
    const float* __restrict__ eps_emit, const f16* __restrict__ pk,
    const float* __restrict__ g1b, const float* __restrict__ g2b,
    const float* __restrict__ p1b, const float* __restrict__ p2b,
    const float* __restrict__ tmub, const float* __restrict__ tlvb,
    const float* __restrict__ e1b, const float* __restrict__ e2b,
    const float* __restrict__ emub, const float* __restrict__ em_logvar,
    float* __restrict__ partials) {
  __shared__ __align__(16) f16 sb256[4][16 * 264];
  __shared__ __align__(16) f16 sb128[4][16 * 136];
  __shared__ float wsum[4][2];
  const int tid = threadIdx.x, lane = tid & 63, w = tid >> 6;
  const int colv = lane & 15, rb = (lane >> 4) << 2;
  const int m0 = blockIdx.x * 64 + w * 16;
  const int t = m0 >> 8, b0 = m0 & 255;
  f16* B256 = &sb256[w][0];
  f16* B128 = &sb128[w][0];

  f16x8 zp[4], zt[4];
  const f16* zpr = z_all + ((size_t)t * BATCH + b0) * ZDIM;
#pragma unroll
  for (int ks = 0; ks < 4; ++ks) {
    zp[ks] = *(const f16x8*)(zpr + (size_t)colv * ZDIM + ks * 32 + ((lane >> 4) << 3));
    zt[ks] = *(const f16x8*)(zpr + (size_t)BATCH * ZDIM + (size_t)colv * ZDIM + ks * 32 + ((lane >> 4) << 3));
  }

  f32x4 a16[16], a8[8];
  f16x8 af[8], af4[4];
  zacc<16>(a16); gemm_regA<4, 16>(zp, pk + PK_G1, lane, a16);
  store_relu<16>(a16, g1b, B256, 264, lane); ldsfence();
  load_af<8>(B256, 264, lane, af); ldsfence();
  zacc<8>(a8); gemm_regA<8, 8>(af, pk + PK_G2, lane, a8);
  f32x4 gate[8];
#pragma unroll
  for (int j = 0; j < 8; ++j)
#pragma unroll
    for (int r = 0; r < 4; ++r)
      gate[j][r] = 1.f / (1.f + expf(-(a8[j][r] + g2b[j * 16 + colv])));
  zacc<16>(a16); gemm_regA<4, 16>(zp, pk + PK_P1, lane, a16);
  store_relu<16>(a16, p1b, B256, 264, lane); ldsfence();
  load_af<8>(B256, 264, lane, af); ldsfence();
  zacc<8>(a8); gemm_regA<8, 8>(af, pk + PK_P2, lane, a8);
  f32x4 prop[8];
#pragma unroll
  for (int j = 0; j < 8; ++j)
#pragma unroll
    for (int r = 0; r < 4; ++r) {
      float v = a8[j][r] + p2b[j * 16 + colv];
      prop[j][r] = v;
      B128[(rb + r) * 136 + j * 16 + colv] = (f16)fmaxf(v, 0.f);
    }
  ldsfence();
  zacc<8>(a8); gemm_regA<4, 8>(zp, pk + PK_TMU, lane, a8);
  f32x4 prmu[8];
#pragma unroll
  for (int j = 0; j < 8; ++j)
#pragma unroll
    for (int r = 0; r < 4; ++r) {
      float gg = gate[j][r];
      prmu[j][r] = (1.f - gg) * (a8[j][r] + tmub[j * 16 + colv]) + gg * prop[j][r];
    }
  load_af<4>(B128, 136, lane, af4); ldsfence();
  zacc<8>(a8); gemm_regA<4, 8>(af4, pk + PK_TLV, lane, a8);
  f32x4 prlv[8];
#pragma unroll
  for (int j = 0; j < 8; ++j)
#pragma unroll
    for (int r = 0; r < 4; ++r) prlv[j][r] = a8[j][r] + tlvb[j * 16 + colv];
  zacc<16>(a16); gemm_regA<4, 16>(zt, pk + PK_E1, lane, a16);
  store_relu<16>(a16, e1b, B256, 264, lane); ldsfence();
  load_af<8>(B256, 264, lane, af); ldsfence();
  zacc<16>(a16); gemm_regA<8, 16>(af, pk + PK_E2, lane, a16);
  store_relu<16>(a16, e2b, B256, 264, lane); ldsfence();
  load_af<8>(B256, 264, lane, af); ldsfence();
  zacc<8>(a8); gemm_regA<8, 8>(af, pk + PK_EMU, lane, a8);
  float srec = 0.f, skl = 0.f;
#pragma unroll
  for (int j = 0; j < 8; ++j)
#pragma unroll
    for (int r = 0; r < 4; ++r) {
      int row = rb + r, n = j * 16 + colv;
      size_t tb = (size_t)t * BATCH + b0 + row;
      float xt = a8[j][r] + emub[n] + eps_emit[tb * DIMX + n] * expf(0.5f * em_logvar[n]);
      float dy = xt - y[((size_t)(b0 + row) * T_LEN + t) * DIMX + n];
      srec += dy * dy;
      float m_ = (float)mu_all[tb * ZDIM + n], l_ = (float)lv_all[tb * ZDIM + n];
      float dm = m_ - prmu[j][r];
      skl += 0.5f * (prlv[j][r] - l_ + (expf(l_) + dm * dm) * expf(-prlv[j][r]) - 1.f);
    }
#pragma unroll
  for (int off = 32; off; off >>= 1) {
    srec += __shfl_xor(srec, off);
    skl += __shfl_xor(skl, off);
  }
  if (lane == 0) { wsum[w][0] = srec; wsum[w][1] = skl; }
  __syncthreads();
  if (tid == 0) {
    partials[blockIdx.x * 2 + 0] = wsum[0][0] + wsum[1][0] + wsum[2][0] + wsum[3][0];
    partials[blockIdx.x * 2 + 1] = wsum[0][1] + wsum[1][1] + wsum[2][1] + wsum[3][1];
  }
}

// =====================================================================
__global__ void finalize_kernel(const float* __restrict__ partials, float* __restrict__ out) {
  __shared__ float sm[256][2];
  int tid = threadIdx.x;
  float r = 0.f, kk = 0.f;
  for (int i = tid; i < 2048; i += 256) {
    r += partials[2 * i];
    kk += partials[2 * i + 1];
  }
  sm[tid][0] = r; sm[tid][1] = kk;
  __syncthreads();
  for (int off = 128; off; off >>= 1) {
    if (tid < off) { sm[tid][0] += sm[tid + off][0]; sm[tid][1] += sm[tid + off][1]; }
    __syncthreads();
  }
  if (tid == 0) {
    out[0] = sm[0][0] / (131072.f * 128.f);
    out[1] = sm[0][1] / 131072.f;
  }
}

// =====================================================================
extern "C" void kernel_launch(void* const* d_in, const int* in_sizes, int n_in,
                              void* d_out, int out_size, void* d_ws, size_t ws_size,
                              hipStream_t stream) {
  (void)in_sizes; (void)n_in; (void)out_size;
  const float* x        = (const float*)d_in[0];
  const float* y        = (const float*)d_in[1];
  const float* eps_comb = (const float*)d_in[2];
  const float* eps_emit = (const float*)d_in[3];
  const float* wih = (const float*)d_in[4];
  const float* whh = (const float*)d_in[5];
  const float* bih = (const float*)d_in[6];
  const float* bhh = (const float*)d_in[7];
  const float* h0  = (const float*)d_in[8];
  const float* zq0 = (const float*)d_in[9];
  const float* g1W = (const float*)d_in[10]; const float* g1b = (const float*)d_in[11];
  const float* g2W = (const float*)d_in[12]; const float* g2b = (const float*)d_in[13];
  const float* p1W = (const float*)d_in[14]; const float* p1b = (const float*)d_in[15];
  const float* p2W = (const float*)d_in[16]; const float* p2b = (const float*)d_in[17];
  const float* tmuW = (const float*)d_in[18]; const float* tmub = (const float*)d_in[19];
  const float* tlvW = (const float*)d_in[20]; const float* tlvb = (const float*)d_in[21];
  const float* chW = (const float*)d_in[22]; const float* chb = (const float*)d_in[23];
  const float* cmW = (const float*)d_in[24]; const float* cmb = (const float*)d_in[25];
  const float* clW = (const float*)d_in[26]; const float* clb = (const float*)d_in[27];
  const float* e1W = (const float*)d_in[28]; const float* e1b = (const float*)d_in[29];
  const float* e2W = (const float*)d_in[30]; const float* e2b = (const float*)d_in[31];
  const float* emW = (const float*)d_in[32]; const float* emb = (const float*)d_in[33];
  const float* elv = (const float*)d_in[34];

  char* ws = (char*)d_ws;
  f16*  xw      = (f16*)(ws + WS_XW);
  f16*  z_all   = (f16*)(ws + WS_Z);
  f16*  mu_all  = (f16*)(ws + WS_MU);
  f16*  lv_all  = (f16*)(ws + WS_LV);
  f16*  pk      = (f16*)(ws + WS_PK);
  float* partials = (float*)(ws + WS_PART);
  unsigned* flags = (unsigned*)(ws + WS_PROG);
  float* out = (float*)d_out;
  if (ws_size < WS_END) return;

  zero_prog_kernel<<<dim3(1), dim3(64), 0, stream>>>(flags);

  PackTab tb;
  unsigned wg = 0; int ei = 0;
#define PACK(S1, S2, NS_, K_, N_, OFF) \
  tb.e[ei] = PackEnt{S1, S2, NS_, K_, N_, OFF, wg}; wg += (unsigned)((K_) * (N_)) / 256; ++ei;
  PACK(wih, wih, 512, 128, 512, PK_WIH);
  PACK(whh, whh, 512, 512, 512, PK_WHH);
  PACK(g1W, g1W, 256, 128, 256, PK_G1);
  PACK(g2W, g2W, 128, 256, 128, PK_G2);
  PACK(p1W, p1W, 256, 128, 256, PK_P1);
  PACK(p2W, p2W, 128, 256, 128, PK_P2);
  PACK(tmuW, tmuW, 128, 128, 128, PK_TMU);
  PACK(tlvW, tlvW, 128, 128, 128, PK_TLV);
  PACK(chW, chW, 512, 128, 512, PK_CBH);
  PACK(cmW, clW, 128, 512, 256, PK_CBML);
  PACK(e1W, e1W, 256, 128, 256, PK_E1);
  PACK(e2W, e2W, 256, 256, 256, PK_E2);
  PACK(emW, emW, 128, 256, 128, PK_EMU);
#undef PACK
  pack_all_kernel<<<dim3(wg), dim3(256), 0, stream>>>(tb, pk);

  scan_pipe_kernel<<<dim3(64), dim3(512), 0, stream>>>(
      pk, h0, zq0, chb, cmb, clb, eps_comb, xw, z_all, mu_all, lv_all,
      x, bih, bhh, flags);
  dpar_kernel<<<dim3(2048), dim3(256), 0, stream>>>(z_all, mu_all, lv_all, y, eps_emit, pk,
                                                    g1b, g2b, p1b, p2b, tmub, tlvb, e1b, e2b,
                                                    emb, elv, partials);
  finalize_kernel<<<dim3(1), dim3(256), 0, stream>>>(partials, out);
}

// Round 14
// 2825.591 us; speedup vs baseline: 1.0013x; 1.0013x over previous
//
#include <hip/hip_runtime.h>

// Deep Kalman Filter inference, MI355X/gfx950.
// pack_all, xw (2048 WG, serial), scan_pipe (32 WG x 512 thr: 16 rnn +
// 16 zscan, chunked one-way flag sync), dpar (2048 WG), finalize.
// R13 lesson: multi-role kernels share ONE register allocation; the
// producer branch (acc[32]) pushed the 8-wave rnn branch into scratch
// spill (FETCH 211->636MB). Fix: two-branch-only scan kernel with the
// R5/R6 512-thread bodies (2 waves/SIMD, latency-hiding, spill-free).
// R9: concurrent bulk kills the scan -> xw serial, dpar separate.
// R10: dpar needs occupancy. R11: staged m_st epilogue (coalescing).
// R2: coarse one-way sync. R3: on-chip weight budget. R4/R5: pin via asm.

#define T_LEN 512
#define BATCH 256
#define DIMX  128
#define ZDIM  128
#define RHD   512
#define CHUNK 32

typedef _Float16 f16;
typedef _Float16 f16x4 __attribute__((ext_vector_type(4)));
typedef _Float16 f16x8 __attribute__((ext_vector_type(8)));
typedef float    f32x4 __attribute__((ext_vector_type(4)));

#define MFMA16(a,b,c) __builtin_amdgcn_mfma_f32_16x16x32_f16((a),(b),(c),0,0,0)

// ---- packed weight element offsets (f16 elements) ----
#define PK_WIH  0u
#define PK_WHH  65536u
#define PK_G1   327680u
#define PK_G2   360448u
#define PK_P1   393216u
#define PK_P2   425984u
#define PK_TMU  458752u
#define PK_TLV  475136u
#define PK_CBH  491520u
#define PK_CBML 557056u
#define PK_E1   688128u
#define PK_E2   720896u
#define PK_EMU  786432u

// ---- workspace byte offsets ----
#define WS_XW   0ull                          // f16 [T][B][RH]: xw in, h out (aliased)
#define WS_Z    (WS_XW  + 134217728ull)       // f16 [T+1][B][Z]
#define WS_MU   (WS_Z   + 33619968ull)        // f16 [T][B][Z]
#define WS_LV   (WS_MU  + 33554432ull)        // f16 [T][B][Z]
#define WS_PK   (WS_LV  + 33554432ull)        // f16 packed weights
#define WS_PART (WS_PK  + 1638400ull)         // f32 [2048][2]
#define WS_PROG (WS_PART + 16384ull)          // u32 prog[16]
#define WS_END  (WS_PROG + 256ull)

// =====================================================================
// helpers
// =====================================================================
__device__ __forceinline__ void ldsfence() {
  asm volatile("s_waitcnt lgkmcnt(0)" ::: "memory");
  __builtin_amdgcn_sched_barrier(0);
}

// lgkm-only workgroup barrier (global ops stay in flight).
__device__ __forceinline__ void lbar() {
  asm volatile("s_waitcnt lgkmcnt(0)" ::: "memory");
  __builtin_amdgcn_s_barrier();
  asm volatile("" ::: "memory");
}

// Anti-rematerialization pin.
__device__ __forceinline__ void pin8(f16x8& v) {
  f32x4 t = __builtin_bit_cast(f32x4, v);
  asm volatile("" : "+v"(t));
  v = __builtin_bit_cast(f16x8, t);
}

template<int N>
__device__ __forceinline__ void zacc(f32x4* a) {
  f32x4 z = {0.f, 0.f, 0.f, 0.f};
#pragma unroll
  for (int i = 0; i < N; ++i) a[i] = z;
}

__device__ __forceinline__ f16x8 cvt8(const float* p) {
  float4 a = *(const float4*)p, b = *(const float4*)(p + 4);
  f16x8 r;
  r[0] = (f16)a.x; r[1] = (f16)a.y; r[2] = (f16)a.z; r[3] = (f16)a.w;
  r[4] = (f16)b.x; r[5] = (f16)b.y; r[6] = (f16)b.z; r[7] = (f16)b.w;
  return r;
}

// XOR swizzle: 16B-chunk of row r at f16-col c -> c ^ ((r&7)<<3)
__device__ __forceinline__ int swz(int row, int col) {
  return (row << 9) + (col ^ ((row & 7) << 3));     // stride 512 f16
}
__device__ __forceinline__ int swz128(int row, int col) {
  return (row << 7) + (col ^ ((row & 7) << 3));     // stride 128 f16
}

// (dpar helpers)
template<int KS>
__device__ __forceinline__ void load_af(const f16* src, int sstr, int lane, f16x8* af) {
#pragma unroll
  for (int ks = 0; ks < KS; ++ks)
    af[ks] = *(const f16x8*)(src + (lane & 15) * sstr + ks * 32 + ((lane >> 4) << 3));
}

template<int KS, int NT>
__device__ __forceinline__ void gemm_regA(const f16x8* af, const f16* __restrict__ bp,
                                          int lane, f32x4* acc) {
#pragma unroll
  for (int ks = 0; ks < KS; ++ks)
#pragma unroll
    for (int j = 0; j < NT; ++j) {
      f16x8 bf = *(const f16x8*)(bp + (((size_t)(ks * NT + j)) << 9) + (lane << 3));
      acc[j] = MFMA16(af[ks], bf, acc[j]);
    }
}

template<int NT>
__device__ __forceinline__ void store_relu(const f32x4* acc, const float* __restrict__ bias,
                                           f16* dst, int dstr, int lane) {
  int colv = lane & 15, rb = (lane >> 4) << 2;
#pragma unroll
  for (int j = 0; j < NT; ++j)
#pragma unroll
    for (int r = 0; r < 4; ++r)
      dst[(rb + r) * dstr + j * 16 + colv] = (f16)fmaxf(acc[j][r] + bias[j * 16 + colv], 0.f);
}

__device__ __forceinline__ unsigned ldflag(const unsigned* p) {
  return __hip_atomic_load(p, __ATOMIC_RELAXED, __HIP_MEMORY_SCOPE_AGENT);
}

// =====================================================================
// pack_all: all 13 matrices. W[K][N] fp32 -> fp16 frags (fi = ks*(N/16)+nt)
// =====================================================================
struct PackEnt { const float* s1; const float* s2; int nsplit, K, N; unsigned dst, wg0; };
struct PackTab { PackEnt e[13]; };

__global__ void pack_all_kernel(PackTab tb, f16* __restrict__ pk) {
  int i = 0;
#pragma unroll
  for (int k = 1; k < 13; ++k)
    if (blockIdx.x >= tb.e[k].wg0) i = k;
  const PackEnt& E = tb.e[i];
  int idx = (blockIdx.x - E.wg0) * 256 + threadIdx.x;
  if (idx >= E.K * E.N) return;
  int j = idx & 7, l = (idx >> 3) & 63, fi = idx >> 9;
  int NTt = E.N >> 4;
  int nt = fi % NTt, ks = fi / NTt;
  int k = ks * 32 + ((l >> 4) << 3) + j;
  int n = (nt << 4) + (l & 15);
  float v;
  if (n < E.nsplit) v = E.s1[(size_t)k * E.nsplit + n];
  else              v = E.s2[(size_t)k * (E.N - E.nsplit) + (n - E.nsplit)];
  pk[E.dst + idx] = (f16)v;
}

__global__ void zero_prog_kernel(unsigned* __restrict__ p) {
  if (threadIdx.x < 64)
    __hip_atomic_store(p + threadIdx.x, 0u, __ATOMIC_RELAXED, __HIP_MEMORY_SCOPE_AGENT);
}

// =====================================================================
// xw = x @ Wih + (bih + bhh), f16 out. 2048 WG x 256 thr. (serial)
// =====================================================================
__global__ __launch_bounds__(256) void xw_kernel(
    const float* __restrict__ x, const f16* __restrict__ pk,
    const float* __restrict__ bih, const float* __restrict__ bhh,
    f16* __restrict__ xw) {
  __shared__ float bs[512];
  const int tid = threadIdx.x, lane = tid & 63, w = tid >> 6;
  const int colv = lane & 15, l4 = lane >> 4;
  const int m0 = blockIdx.x * 64 + w * 16;
  const int t = m0 >> 8, b0 = m0 & 255;
  for (int i = tid; i < 512; i += 256) bs[i] = bih[i] + bhh[i];
  __syncthreads();
  f16x8 xB[4];
  const float* xr = x + ((size_t)(b0 + colv) * T_LEN + t) * DIMX;
#pragma unroll
  for (int ks = 0; ks < 4; ++ks) xB[ks] = cvt8(xr + ks * 32 + l4 * 8);
  f32x4 acc[32]; zacc<32>(acc);
#pragma unroll
  for (int ks = 0; ks < 4; ++ks)
#pragma unroll
    for (int mt = 0; mt < 32; ++mt)
      acc[mt] = MFMA16(*(const f16x8*)(pk + PK_WIH + ((size_t)(ks * 32 + mt) << 9) + (lane << 3)),
                       xB[ks], acc[mt]);
  f16* xo = xw + ((size_t)t * BATCH + b0 + colv) * RHD;
#pragma unroll
  for (int mt = 0; mt < 32; ++mt) {
    f16x4 v;
#pragma unroll
    for (int r = 0; r < 4; ++r) v[r] = (f16)(acc[mt][r] + bs[mt * 16 + l4 * 4 + r]);
    *(f16x4*)(xo + mt * 16 + l4 * 4) = v;
  }
}

// =====================================================================
// scan_pipe: 32 WGs x 512 thr (8 waves, 2/SIMD; 1 WG/CU via 144KB LDS).
// WG 0..15:  rnn role (R5 body): Whh ks0..11 regs (192), ks12..15 LDS.
// WG 16..31: zscan role (R6 body): cbh regs, cbml ks0..11 regs + 64KB LDS.
// Two branches only -> shared regalloc fits 2 waves/SIMD without spill.
// =====================================================================
__global__ __launch_bounds__(512, 2) void scan_pipe_kernel(
    const f16* __restrict__ pk, const float* __restrict__ h0,
    const float* __restrict__ zq0, const float* __restrict__ chb,
    const float* __restrict__ cmb, const float* __restrict__ clb,
    const float* __restrict__ eps_comb, f16* __restrict__ xw,
    f16* __restrict__ z_all, f16* __restrict__ mu_all, f16* __restrict__ lv_all,
    unsigned* __restrict__ prog) {
  __shared__ __align__(16) f16 lds[73728];  // 144 KB union
  const int tid = threadIdx.x, lane = tid & 63, w = tid >> 6;
  const int colv = lane & 15, l4 = lane >> 4;

  if (blockIdx.x < 16) {
    // ------------------- RNN role (8 waves, R5 body) -------------------
    const int g = blockIdx.x, b0 = g * 16;
    f16* whh_lds = lds;          // 65536 f16 (ks 12..15)
    f16* h_st = lds + 65536;     // 8192 f16, swizzled [16][512]
    {
      const uint4* src = (const uint4*)(pk + PK_WHH + 196608u);
      for (int i = tid; i < 8192; i += 512) ((uint4*)whh_lds)[i] = src[i];
    }
    f16x8 whhA[4][12];
#pragma unroll
    for (int mt = 0; mt < 4; ++mt)
#pragma unroll
      for (int ks = 0; ks < 12; ++ks) {
        whhA[mt][ks] = *(const f16x8*)(pk + PK_WHH +
            ((size_t)(ks * 32 + 4 * w + mt) << 9) + (lane << 3));
        pin8(whhA[mt][ks]);
      }
    for (int i = tid; i < 8192; i += 512) h_st[swz(i >> 9, i & 511)] = (f16)h0[i & 511];
    __syncthreads();

    const int off0 = (4 * w) * 16 + l4 * 4;
    f16* xp = xw + (size_t)(b0 + colv) * RHD;
    f16x4 xwc[4], xwn[4];
#pragma unroll
    for (int mt = 0; mt < 4; ++mt) xwc[mt] = *(const f16x4*)(xp + off0 + mt * 16);

    for (int c = 0; c < T_LEN / CHUNK; ++c) {
#pragma unroll 1
      for (int tt = 0; tt < CHUNK; ++tt) {
        int t = c * CHUNK + tt;
        f16* xpn = (t < T_LEN - 1) ? xp + (size_t)BATCH * RHD : xp;
#pragma unroll
        for (int mt = 0; mt < 4; ++mt) xwn[mt] = *(const f16x4*)(xpn + off0 + mt * 16);

        f32x4 acc[4]; zacc<4>(acc);
#pragma unroll
        for (int kc = 0; kc < 6; ++kc) {
          f16x8 B2[2];
#pragma unroll
          for (int kk = 0; kk < 2; ++kk)
            B2[kk] = *(const f16x8*)&h_st[swz(colv, (kc * 2 + kk) * 32 + l4 * 8)];
#pragma unroll
          for (int kk = 0; kk < 2; ++kk)
#pragma unroll
            for (int mt = 0; mt < 4; ++mt)
              acc[mt] = MFMA16(whhA[mt][kc * 2 + kk], B2[kk], acc[mt]);
        }
#pragma unroll
        for (int kc = 0; kc < 2; ++kc) {
          f16x8 B2[2];
#pragma unroll
          for (int kk = 0; kk < 2; ++kk)
            B2[kk] = *(const f16x8*)&h_st[swz(colv, (12 + kc * 2 + kk) * 32 + l4 * 8)];
#pragma unroll
          for (int kk = 0; kk < 2; ++kk)
#pragma unroll
            for (int mt = 0; mt < 4; ++mt)
              acc[mt] = MFMA16(*(const f16x8*)(whh_lds +
                  ((((kc * 2 + kk) * 32 + 4 * w + mt) << 6) + lane) * 8), B2[kk], acc[mt]);
        }
        lbar();  // B1: h_st reads done
#pragma unroll
        for (int mt = 0; mt < 4; ++mt) {
          f16x4 h4;
#pragma unroll
          for (int r = 0; r < 4; ++r)
            h4[r] = (f16)fmaxf(acc[mt][r] + (float)xwc[mt][r], 0.f);
          *(f16x4*)&h_st[swz(colv, off0 + mt * 16)] = h4;
          *(f16x4*)(xp + off0 + mt * 16) = h4;  // h overwrites xw[t]
        }
        lbar();  // B2
        xp = xpn;
#pragma unroll
        for (int mt = 0; mt < 4; ++mt) xwc[mt] = xwn[mt];
      }
      __syncthreads();  // drains all waves' vmem (h stores at L2)
      if (tid == 0)
        __hip_atomic_store(prog + g, (unsigned)(c + 1), __ATOMIC_RELEASE,
                           __HIP_MEMORY_SCOPE_AGENT);
    }
  } else {
    // ------------------- zscan role (8 waves, R6 body) -------------------
    const int g = blockIdx.x - 16, b0 = g * 16;
    f16* cbml_lds = lds;           // 32768 f16 (ks 12..15)
    f16* hc_st = lds + 32768;      // 8192 f16, swizzled [16][512]
    f16* z_st  = lds + 40960;      // 2048 f16, swizzled [16][128]
    f16* m_st  = lds + 43008;      // [16][264] f16
    {
      const uint4* src = (const uint4*)(pk + PK_CBML + 98304u);
      for (int i = tid; i < 4096; i += 512) ((uint4*)cbml_lds)[i] = src[i];
    }
    f16x8 cbhA[4][4];
#pragma unroll
    for (int mt = 0; mt < 4; ++mt)
#pragma unroll
      for (int ks = 0; ks < 4; ++ks) {
        cbhA[mt][ks] = *(const f16x8*)(pk + PK_CBH +
            ((size_t)(ks * 32 + 4 * w + mt) << 9) + (lane << 3));
        pin8(cbhA[mt][ks]);
      }
    f16x8 cbmlA[2][12];
#pragma unroll
    for (int mt = 0; mt < 2; ++mt)
#pragma unroll
      for (int ks = 0; ks < 12; ++ks) {
        cbmlA[mt][ks] = *(const f16x8*)(pk + PK_CBML +
            ((size_t)(ks * 16 + 2 * w + mt) << 9) + (lane << 3));
        pin8(cbmlA[mt][ks]);
      }
    f16x4 chbv[4];
#pragma unroll
    for (int mt = 0; mt < 4; ++mt)
#pragma unroll
      for (int r = 0; r < 4; ++r)
        chbv[mt][r] = (f16)chb[(4 * w + mt) * 16 + l4 * 4 + r];
    float mb[2][4];
#pragma unroll
    for (int mt = 0; mt < 2; ++mt)
#pragma unroll
      for (int r = 0; r < 4; ++r) {
        int d = (2 * w + mt) * 16 + l4 * 4 + r;
        mb[mt][r] = (d < 128) ? cmb[d] : clb[d - 128];
      }
    for (int i = tid; i < 2048; i += 512) {
      f16 zv = (f16)zq0[i & 127];
      z_st[swz128(i >> 7, i & 127)] = zv;
      z_all[(size_t)(b0 + (i >> 7)) * ZDIM + (i & 127)] = zv;  // z_all[0]
    }
    __syncthreads();

    const int hoff = (4 * w) * 16 + l4 * 4;
    const int be = tid >> 5, d0 = (tid & 31) * 4;
    const f16* hp = xw + (size_t)(b0 + colv) * RHD;
    const float* epb = eps_comb + (size_t)(b0 + be) * ZDIM + d0;
    f16x4 hvc[4], hvn[4];

    for (int c = 0; c < T_LEN / CHUNK; ++c) {
      if (tid == 0) {
        while (ldflag(prog + g) < (unsigned)(c + 1)) __builtin_amdgcn_s_sleep(2);
      }
      __syncthreads();
      __builtin_amdgcn_fence(__ATOMIC_ACQUIRE, "agent");
      {
        const f16* hpt = hp + (size_t)(c * CHUNK) * BATCH * RHD;
#pragma unroll
        for (int mt = 0; mt < 4; ++mt) hvc[mt] = *(const f16x4*)(hpt + hoff + mt * 16);
      }
#pragma unroll 1
      for (int tt = 0; tt < CHUNK; ++tt) {
        int t = c * CHUNK + tt;
        float4 ep = *(const float4*)(epb + (size_t)t * BATCH * ZDIM);

        // GEMM1: cbh @ z (M=512, K=128)
        f16x8 zB[4];
#pragma unroll
        for (int ks = 0; ks < 4; ++ks)
          zB[ks] = *(const f16x8*)&z_st[swz128(colv, ks * 32 + l4 * 8)];
        f32x4 a1[4]; zacc<4>(a1);
#pragma unroll
        for (int ks = 0; ks < 4; ++ks)
#pragma unroll
          for (int mt = 0; mt < 4; ++mt)
            a1[mt] = MFMA16(cbhA[mt][ks], zB[ks], a1[mt]);
        // epi1: hc = 0.5*(tanh(a1+chb) + h)
#pragma unroll
        for (int mt = 0; mt < 4; ++mt) {
          f16x4 hc4;
#pragma unroll
          for (int r = 0; r < 4; ++r) {
            float cs = a1[mt][r] + (float)chbv[mt][r];
            float ex = __builtin_amdgcn_exp2f(cs * 2.885390082f);   // e^(2x)
            float th = 1.f - 2.f * __builtin_amdgcn_rcpf(ex + 1.f); // tanh
            hc4[r] = (f16)(0.5f * (th + (float)hvc[mt][r]));
          }
          *(f16x4*)&hc_st[swz(colv, hoff + mt * 16)] = hc4;
        }
        lbar();  // B1: hc ready (and z_st reads done)
        // prefetch next-step h (within chunk only; overlaps GEMM2)
        if (tt < CHUNK - 1) {
          const f16* hpt = hp + (size_t)(t + 1) * BATCH * RHD;
#pragma unroll
          for (int mt = 0; mt < 4; ++mt) hvn[mt] = *(const f16x4*)(hpt + hoff + mt * 16);
        }
        // GEMM2: cbml @ hc (M=256, K=512); ks 0..11 reg A, 12..15 LDS A
        f32x4 a2[2]; zacc<2>(a2);
#pragma unroll
        for (int kc = 0; kc < 6; ++kc) {
          f16x8 hcB[2];
#pragma unroll
          for (int kk = 0; kk < 2; ++kk)
            hcB[kk] = *(const f16x8*)&hc_st[swz(colv, (kc * 2 + kk) * 32 + l4 * 8)];
#pragma unroll
          for (int kk = 0; kk < 2; ++kk)
#pragma unroll
            for (int mt = 0; mt < 2; ++mt)
              a2[mt] = MFMA16(cbmlA[mt][kc * 2 + kk], hcB[kk], a2[mt]);
        }
#pragma unroll
        for (int kc = 0; kc < 2; ++kc) {
          f16x8 hcB[2];
#pragma unroll
          for (int kk = 0; kk < 2; ++kk)
            hcB[kk] = *(const f16x8*)&hc_st[swz(colv, (12 + kc * 2 + kk) * 32 + l4 * 8)];
#pragma unroll
          for (int kk = 0; kk < 2; ++kk)
#pragma unroll
            for (int mt = 0; mt < 2; ++mt)
              a2[mt] = MFMA16(*(const f16x8*)(cbml_lds +
                  ((((kc * 2 + kk) * 16 + 2 * w + mt) << 6) + lane) * 8), hcB[kk], a2[mt]);
        }
#pragma unroll
        for (int mt = 0; mt < 2; ++mt) {
          f16x4 v;
#pragma unroll
          for (int r = 0; r < 4; ++r) v[r] = (f16)(a2[mt][r] + mb[mt][r]);  // biased
          *(f16x4*)&m_st[colv * 264 + (2 * w + mt) * 16 + l4 * 4] = v;
        }
        lbar();  // B2: mu|lv ready
        // z epilogue: thread -> (batch be, dims d0..d0+3); m_st biased
        {
          f16x4 muf = *(const f16x4*)&m_st[be * 264 + d0];
          f16x4 lvf = *(const f16x4*)&m_st[be * 264 + 128 + d0];
          float epv[4] = {ep.x, ep.y, ep.z, ep.w};
          f16x4 z4;
#pragma unroll
          for (int r = 0; r < 4; ++r) {
            float mu = (float)muf[r], lv = (float)lvf[r];
            z4[r] = (f16)(mu + epv[r] * __builtin_amdgcn_exp2f(lv * 0.7213475204f));
          }
          *(f16x4*)&z_st[swz128(be, d0)] = z4;
          size_t o = ((size_t)t * BATCH + b0 + be) * ZDIM + d0;
          *(f16x4*)(z_all + o + (size_t)BATCH * ZDIM) = z4;  // slot t+1
          *(f16x4*)(mu_all + o) = muf;
          *(f16x4*)(lv_all + o) = lvf;
        }
        lbar();  // B3: z_st/m_st safe for next step
#pragma unroll
        for (int mt = 0; mt < 4; ++mt) hvc[mt] = hvn[mt];
      }
    }
  }
}

// =====================================================================
// Phase D: parallel transition/emitter/losses over all (t,b). (R8 form)
// =====================================================================
__global__ __launch_bounds__(256) void dpar_kernel(
    const f16* __restrict__ z_all, const f16* __restrict__ mu_all,
    const f16* __restrict__ lv_all, const float* __restrict__ y,
    const float* __restrict__ eps_emit, const f16* __restrict__ pk,
    const float* __restrict__ g1b, const float* __restrict__ g2b,
    const float* __restrict__ p1b, const float* __restrict__ p2b,
    const float* __restrict__ tmub, const float* __restrict__ tlvb,
    const float* __restrict__ e1b, const float* __restrict__ e2b,
    const float* __restrict__ emub, const float* __restrict__ em_logvar,
    float* __restrict__ partials) {
  __shared__ __align__(16) f16 sb256[4][16 * 264];
  __shared__ __align__(16) f16 sb128[4][16 * 136];
  __shared__ float wsum[4][2];
  const int tid = threadIdx.x, lane = tid & 63, w = tid >> 6;
  const int colv = lane & 15, rb = (lane >> 4) << 2;
  const int m0 = blockIdx.x * 64 + w * 16;
  const int t = m0 >> 8, b0 = m0 & 255;
  f16* B256 = &sb256[w][0];
  f16* B128 = &sb128[w][0];

  f16x8 zp[4], zt[4];
  const f16* zpr = z_all + ((size_t)t * BATCH + b0) * ZDIM;
#pragma unroll
  for (int ks = 0; ks < 4; ++ks) {
    zp[ks] = *(const f16x8*)(zpr + (size_t)colv * ZDIM + ks * 32 + ((lane >> 4) << 3));
    zt[ks] = *(const f16x8*)(zpr + (size_t)BATCH * ZDIM + (size_t)colv * ZDIM + ks * 32 + ((lane >> 4) << 3));
  }

  f32x4 a16[16], a8[8];
  f16x8 af[8], af4[4];
  zacc<16>(a16); gemm_regA<4, 16>(zp, pk + PK_G1, lane, a16);
  store_relu<16>(a16, g1b, B256, 264, lane); ldsfence();
  load_af<8>(B256, 264, lane, af); ldsfence();
  zacc<8>(a8); gemm_regA<8, 8>(af, pk + PK_G2, lane, a8);
  f32x4 gate[8];
#pragma unroll
  for (int j = 0; j < 8; ++j)
#pragma unroll
    for (int r = 0; r < 4; ++r)
      gate[j][r] = 1.f / (1.f + expf(-(a8[j][r] + g2b[j * 16 + colv])));
  zacc<16>(a16); gemm_regA<4, 16>(zp, pk + PK_P1, lane, a16);
  store_relu<16>(a16, p1b, B256, 264, lane); ldsfence();
  load_af<8>(B256, 264, lane, af); ldsfence();
  zacc<8>(a8); gemm_regA<8, 8>(af, pk + PK_P2, lane, a8);
  f32x4 prop[8];
#pragma unroll
  for (int j = 0; j < 8; ++j)
#pragma unroll
    for (int r = 0; r < 4; ++r) {
      float v = a8[j][r] + p2b[j * 16 + colv];
      prop[j][r] = v;
      B128[(rb + r) * 136 + j * 16 + colv] = (f16)fmaxf(v, 0.f);
    }
  ldsfence();
  zacc<8>(a8); gemm_regA<4, 8>(zp, pk + PK_TMU, lane, a8);
  f32x4 prmu[8];
#pragma unroll
  for (int j = 0; j < 8; ++j)
#pragma unroll
    for (int r = 0; r < 4; ++r) {
      float gg = gate[j][r];
      prmu[j][r] = (1.f - gg) * (a8[j][r] + tmub[j * 16 + colv]) + gg * prop[j][r];
    }
  load_af<4>(B128, 136, lane, af4); ldsfence();
  zacc<8>(a8); gemm_regA<4, 8>(af4, pk + PK_TLV, lane, a8);
  f32x4 prlv[8];
#pragma unroll
  for (int j = 0; j < 8; ++j)
#pragma unroll
    for (int r = 0; r < 4; ++r) prlv[j][r] = a8[j][r] + tlvb[j * 16 + colv];
  zacc<16>(a16); gemm_regA<4, 16>(zt, pk + PK_E1, lane, a16);
  store_relu<16>(a16, e1b, B256, 264, lane); ldsfence();
  load_af<8>(B256, 264, lane, af); ldsfence();
  zacc<16>(a16); gemm_regA<8, 16>(af, pk + PK_E2, lane, a16);
  store_relu<16>(a16, e2b, B256, 264, lane); ldsfence();
  load_af<8>(B256, 264, lane, af); ldsfence();
  zacc<8>(a8); gemm_regA<8, 8>(af, pk + PK_EMU, lane, a8);
  float srec = 0.f, skl = 0.f;
#pragma unroll
  for (int j = 0; j < 8; ++j)
#pragma unroll
    for (int r = 0; r < 4; ++r) {
      int row = rb + r, n = j * 16 + colv;
      size_t tb = (size_t)t * BATCH + b0 + row;
      float xt = a8[j][r] + emub[n] + eps_emit[tb * DIMX + n] * expf(0.5f * em_logvar[n]);
      float dy = xt - y[((size_t)(b0 + row) * T_LEN + t) * DIMX + n];
      srec += dy * dy;
      float m_ = (float)mu_all[tb * ZDIM + n], l_ = (float)lv_all[tb * ZDIM + n];
      float dm = m_ - prmu[j][r];
      skl += 0.5f * (prlv[j][r] - l_ + (expf(l_) + dm * dm) * expf(-prlv[j][r]) - 1.f);
    }
#pragma unroll
  for (int off = 32; off; off >>= 1) {
    srec += __shfl_xor(srec, off);
    skl += __shfl_xor(skl, off);
  }
  if (lane == 0) { wsum[w][0] = srec; wsum[w][1] = skl; }
  __syncthreads();
  if (tid == 0) {
    partials[blockIdx.x * 2 + 0] = wsum[0][0] + wsum[1][0] + wsum[2][0] + wsum[3][0];
    partials[blockIdx.x * 2 + 1] = wsum[0][1] + wsum[1][1] + wsum[2][1] + wsum[3][1];
  }
}

// =====================================================================
__global__ void finalize_kernel(const float* __restrict__ partials, float* __restrict__ out) {
  __shared__ float sm[256][2];
  int tid = threadIdx.x;
  float r = 0.f, kk = 0.f;
  for (int i = tid; i < 2048; i += 256) {
    r += partials[2 * i];
    kk += partials[2 * i + 1];
  }
  sm[tid][0] = r; sm[tid][1] = kk;
  __syncthreads();
  for (int off = 128; off; off >>= 1) {
    if (tid < off) { sm[tid][0] += sm[tid + off][0]; sm[tid][1] += sm[tid + off][1]; }
    __syncthreads();
  }
  if (tid == 0) {
    out[0] = sm[0][0] / (131072.f * 128.f);
    out[1] = sm[0][1] / 131072.f;
  }
}

// =====================================================================
extern "C" void kernel_launch(void* const* d_in, const int* in_sizes, int n_in,
                              void* d_out, int out_size, void* d_ws, size_t ws_size,
                              hipStream_t stream) {
  (void)in_sizes; (void)n_in; (void)out_size;
  const float* x        = (const float*)d_in[0];
  const float* y        = (const float*)d_in[1];
  const float* eps_comb = (const float*)d_in[2];
  const float* eps_emit = (const float*)d_in[3];
  const float* wih = (const float*)d_in[4];
  const float* whh = (const float*)d_in[5];
  const float* bih = (const float*)d_in[6];
  const float* bhh = (const float*)d_in[7];
  const float* h0  = (const float*)d_in[8];
  const float* zq0 = (const float*)d_in[9];
  const float* g1W = (const float*)d_in[10]; const float* g1b = (const float*)d_in[11];
  const float* g2W = (const float*)d_in[12]; const float* g2b = (const float*)d_in[13];
  const float* p1W = (const float*)d_in[14]; const float* p1b = (const float*)d_in[15];
  const float* p2W = (const float*)d_in[16]; const float* p2b = (const float*)d_in[17];
  const float* tmuW = (const float*)d_in[18]; const float* tmub = (const float*)d_in[19];
  const float* tlvW = (const float*)d_in[20]; const float* tlvb = (const float*)d_in[21];
  const float* chW = (const float*)d_in[22]; const float* chb = (const float*)d_in[23];
  const float* cmW = (const float*)d_in[24]; const float* cmb = (const float*)d_in[25];
  const float* clW = (const float*)d_in[26]; const float* clb = (const float*)d_in[27];
  const float* e1W = (const float*)d_in[28]; const float* e1b = (const float*)d_in[29];
  const float* e2W = (const float*)d_in[30]; const float* e2b = (const float*)d_in[31];
  const float* emW = (const float*)d_in[32]; const float* emb = (const float*)d_in[33];
  const float* elv = (const float*)d_in[34];

  char* ws = (char*)d_ws;
  f16*  xw      = (f16*)(ws + WS_XW);
  f16*  z_all   = (f16*)(ws + WS_Z);
  f16*  mu_all  = (f16*)(ws + WS_MU);
  f16*  lv_all  = (f16*)(ws + WS_LV);
  f16*  pk      = (f16*)(ws + WS_PK);
  float* partials = (float*)(ws + WS_PART);
  unsigned* prog  = (unsigned*)(ws + WS_PROG);
  float* out = (float*)d_out;
  if (ws_size < WS_END) return;

  zero_prog_kernel<<<dim3(1), dim3(64), 0, stream>>>(prog);

  PackTab tb;
  unsigned wg = 0; int ei = 0;
#define PACK(S1, S2, NS_, K_, N_, OFF) \
  tb.e[ei] = PackEnt{S1, S2, NS_, K_, N_, OFF, wg}; wg += (unsigned)((K_) * (N_)) / 256; ++ei;
  PACK(wih, wih, 512, 128, 512, PK_WIH);
  PACK(whh, whh, 512, 512, 512, PK_WHH);
  PACK(g1W, g1W, 256, 128, 256, PK_G1);
  PACK(g2W, g2W, 128, 256, 128, PK_G2);
  PACK(p1W, p1W, 256, 128, 256, PK_P1);
  PACK(p2W, p2W, 128, 256, 128, PK_P2);
  PACK(tmuW, tmuW, 128, 128, 128, PK_TMU);
  PACK(tlvW, tlvW, 128, 128, 128, PK_TLV);
  PACK(chW, chW, 512, 128, 512, PK_CBH);
  PACK(cmW, clW, 128, 512, 256, PK_CBML);
  PACK(e1W, e1W, 256, 128, 256, PK_E1);
  PACK(e2W, e2W, 256, 256, 256, PK_E2);
  PACK(emW, emW, 128, 256, 128, PK_EMU);
#undef PACK
  pack_all_kernel<<<dim3(wg), dim3(256), 0, stream>>>(tb, pk);

  xw_kernel<<<dim3(2048), dim3(256), 0, stream>>>(x, pk, bih, bhh, xw);
  scan_pipe_kernel<<<dim3(32), dim3(512), 0, stream>>>(
      pk, h0, zq0, chb, cmb, clb, eps_comb, xw, z_all, mu_all, lv_all, prog);
  dpar_kernel<<<dim3(2048), dim3(256), 0, stream>>>(z_all, mu_all, lv_all, y, eps_emit, pk,
                                                    g1b, g2b, p1b, p2b, tmub, tlvb, e1b, e2b,
                                                    emb, elv, partials);
  finalize_kernel<<<dim3(1), dim3(256), 0, stream>>>(partials, out);
}

// Round 15
// 2821.699 us; speedup vs baseline: 1.0027x; 1.0014x over previous
//
#include <hip/hip_runtime.h>

// Deep Kalman Filter inference, MI355X/gfx950.
// pack_all, xw (256 WG, Wih pinned, grid-stride), scan_pipe (32 WG x 256
// thr: 16 rnn + 16 zscan, chunked one-way flag sync), dpar (2048 WG),
// finalize.
// Ledger: R8 structure is the verified best (2522; scan 1724). This round:
// (1) rnn 2->1 barriers/step via h_st double-buffer; Whh 13 reg slices +
//     3 LDS slices (LDS 128KB total, no 160KB risk);
// (2) xw: pin Wih per block, 32 tiles/block (weight traffic 1GB->32MB);
// (3) CHUNK 16 (R10-proven) halves zscan tail.
// R9: no bulk work concurrent with scan. R10: dpar separate (occupancy).
// R11: staged m_st epilogue. R13: no third branch in scan kernel (regalloc).
// R4/R5: pin weights via asm. R8: arch "v" cap 256 (512 unified @1w/SIMD).

#define T_LEN 512
#define BATCH 256
#define DIMX  128
#define ZDIM  128
#define RHD   512
#define CHUNK 16
#define NCHNK 32

typedef _Float16 f16;
typedef _Float16 f16x4 __attribute__((ext_vector_type(4)));
typedef _Float16 f16x8 __attribute__((ext_vector_type(8)));
typedef float    f32x4 __attribute__((ext_vector_type(4)));

#define MFMA16(a,b,c) __builtin_amdgcn_mfma_f32_16x16x32_f16((a),(b),(c),0,0,0)

// ---- packed weight element offsets (f16 elements) ----
#define PK_WIH  0u
#define PK_WHH  65536u
#define PK_G1   327680u
#define PK_G2   360448u
#define PK_P1   393216u
#define PK_P2   425984u
#define PK_TMU  458752u
#define PK_TLV  475136u
#define PK_CBH  491520u
#define PK_CBML 557056u
#define PK_E1   688128u
#define PK_E2   720896u
#define PK_EMU  786432u

// ---- workspace byte offsets ----
#define WS_XW   0ull                          // f16 [T][B][RH]: xw in, h out (aliased)
#define WS_Z    (WS_XW  + 134217728ull)       // f16 [T+1][B][Z]
#define WS_MU   (WS_Z   + 33619968ull)        // f16 [T][B][Z]
#define WS_LV   (WS_MU  + 33554432ull)        // f16 [T][B][Z]
#define WS_PK   (WS_LV  + 33554432ull)        // f16 packed weights
#define WS_PART (WS_PK  + 1638400ull)         // f32 [2048][2]
#define WS_PROG (WS_PART + 16384ull)          // u32 prog[16]
#define WS_END  (WS_PROG + 256ull)

// =====================================================================
// helpers
// =====================================================================
__device__ __forceinline__ void ldsfence() {
  asm volatile("s_waitcnt lgkmcnt(0)" ::: "memory");
  __builtin_amdgcn_sched_barrier(0);
}

// lgkm-only workgroup barrier (global ops stay in flight).
__device__ __forceinline__ void lbar() {
  asm volatile("s_waitcnt lgkmcnt(0)" ::: "memory");
  __builtin_amdgcn_s_barrier();
  asm volatile("" ::: "memory");
}

// Anti-rematerialization pin.
__device__ __forceinline__ void pin8(f16x8& v) {
  f32x4 t = __builtin_bit_cast(f32x4, v);
  asm volatile("" : "+v"(t));
  v = __builtin_bit_cast(f16x8, t);
}

template<int N>
__device__ __forceinline__ void zacc(f32x4* a) {
  f32x4 z = {0.f, 0.f, 0.f, 0.f};
#pragma unroll
  for (int i = 0; i < N; ++i) a[i] = z;
}

__device__ __forceinline__ f16x8 cvt8(const float* p) {
  float4 a = *(const float4*)p, b = *(const float4*)(p + 4);
  f16x8 r;
  r[0] = (f16)a.x; r[1] = (f16)a.y; r[2] = (f16)a.z; r[3] = (f16)a.w;
  r[4] = (f16)b.x; r[5] = (f16)b.y; r[6] = (f16)b.z; r[7] = (f16)b.w;
  return r;
}

// XOR swizzle: 16B-chunk of row r at f16-col c -> c ^ ((r&7)<<3)
__device__ __forceinline__ int swz(int row, int col) {
  return (row << 9) + (col ^ ((row & 7) << 3));     // stride 512 f16
}
__device__ __forceinline__ int swz128(int row, int col) {
  return (row << 7) + (col ^ ((row & 7) << 3));     // stride 128 f16
}

// (dpar helpers)
template<int KS>
__device__ __forceinline__ void load_af(const f16* src, int sstr, int lane, f16x8* af) {
#pragma unroll
  for (int ks = 0; ks < KS; ++ks)
    af[ks] = *(const f16x8*)(src + (lane & 15) * sstr + ks * 32 + ((lane >> 4) << 3));
}

template<int KS, int NT>
__device__ __forceinline__ void gemm_regA(const f16x8* af, const f16* __restrict__ bp,
                                          int lane, f32x4* acc) {
#pragma unroll
  for (int ks = 0; ks < KS; ++ks)
#pragma unroll
    for (int j = 0; j < NT; ++j) {
      f16x8 bf = *(const f16x8*)(bp + (((size_t)(ks * NT + j)) << 9) + (lane << 3));
      acc[j] = MFMA16(af[ks], bf, acc[j]);
    }
}

template<int NT>
__device__ __forceinline__ void store_relu(const f32x4* acc, const float* __restrict__ bias,
                                           f16* dst, int dstr, int lane) {
  int colv = lane & 15, rb = (lane >> 4) << 2;
#pragma unroll
  for (int j = 0; j < NT; ++j)
#pragma unroll
    for (int r = 0; r < 4; ++r)
      dst[(rb + r) * dstr + j * 16 + colv] = (f16)fmaxf(acc[j][r] + bias[j * 16 + colv], 0.f);
}

__device__ __forceinline__ unsigned ldflag(const unsigned* p) {
  return __hip_atomic_load(p, __ATOMIC_RELAXED, __HIP_MEMORY_SCOPE_AGENT);
}

// =====================================================================
// pack_all: all 13 matrices. W[K][N] fp32 -> fp16 frags (fi = ks*(N/16)+nt)
// =====================================================================
struct PackEnt { const float* s1; const float* s2; int nsplit, K, N; unsigned dst, wg0; };
struct PackTab { PackEnt e[13]; };

__global__ void pack_all_kernel(PackTab tb, f16* __restrict__ pk) {
  int i = 0;
#pragma unroll
  for (int k = 1; k < 13; ++k)
    if (blockIdx.x >= tb.e[k].wg0) i = k;
  const PackEnt& E = tb.e[i];
  int idx = (blockIdx.x - E.wg0) * 256 + threadIdx.x;
  if (idx >= E.K * E.N) return;
  int j = idx & 7, l = (idx >> 3) & 63, fi = idx >> 9;
  int NTt = E.N >> 4;
  int nt = fi % NTt, ks = fi / NTt;
  int k = ks * 32 + ((l >> 4) << 3) + j;
  int n = (nt << 4) + (l & 15);
  float v;
  if (n < E.nsplit) v = E.s1[(size_t)k * E.nsplit + n];
  else              v = E.s2[(size_t)k * (E.N - E.nsplit) + (n - E.nsplit)];
  pk[E.dst + idx] = (f16)v;
}

__global__ void zero_prog_kernel(unsigned* __restrict__ p) {
  if (threadIdx.x < 64)
    __hip_atomic_store(p + threadIdx.x, 0u, __ATOMIC_RELAXED, __HIP_MEMORY_SCOPE_AGENT);
}

// =====================================================================
// xw = x @ Wih + (bih + bhh). 256 WG x 256 thr (4 waves); Wih pinned in
// regs (wave w owns dims w*128..+128); 32 tiles of 16 rows per block.
// =====================================================================
__global__ __launch_bounds__(256) void xw_kernel(
    const float* __restrict__ x, const f16* __restrict__ pk,
    const float* __restrict__ bih, const float* __restrict__ bhh,
    f16* __restrict__ xw) {
  __shared__ float bs[512];
  const int tid = threadIdx.x, lane = tid & 63, w = tid >> 6;
  const int colv = lane & 15, l4 = lane >> 4;
  for (int i = tid; i < 512; i += 256) bs[i] = bih[i] + bhh[i];
  f16x8 wihA[8][4];
#pragma unroll
  for (int mt = 0; mt < 8; ++mt)
#pragma unroll
    for (int ks = 0; ks < 4; ++ks) {
      wihA[mt][ks] = *(const f16x8*)(pk + PK_WIH +
          ((size_t)(ks * 32 + w * 8 + mt) << 9) + (lane << 3));
      pin8(wihA[mt][ks]);
    }
  __syncthreads();
#pragma unroll 1
  for (int i = blockIdx.x; i < 8192; i += 256) {   // 8192 tiles of 16 rows
    const int t = i >> 4, b0 = (i & 15) * 16;
    f16x8 xB[4];
    const float* xr = x + ((size_t)(b0 + colv) * T_LEN + t) * DIMX;
#pragma unroll
    for (int ks = 0; ks < 4; ++ks) xB[ks] = cvt8(xr + ks * 32 + l4 * 8);
    f32x4 acc[8]; zacc<8>(acc);
#pragma unroll
    for (int ks = 0; ks < 4; ++ks)
#pragma unroll
      for (int mt = 0; mt < 8; ++mt)
        acc[mt] = MFMA16(wihA[mt][ks], xB[ks], acc[mt]);
    f16* xo = xw + ((size_t)t * BATCH + b0 + colv) * RHD + w * 128;
#pragma unroll
    for (int mt = 0; mt < 8; ++mt) {
      f16x4 v;
#pragma unroll
      for (int r = 0; r < 4; ++r) v[r] = (f16)(acc[mt][r] + bs[w * 128 + mt * 16 + l4 * 4 + r]);
      *(f16x4*)(xo + mt * 16 + l4 * 4) = v;
    }
  }
}

// =====================================================================
// scan_pipe: 32 WGs x 256 thr (4 waves, 1/SIMD -> 512 unified regs).
// WG 0..15:  rnn role: Whh ks0..12 pinned regs (416), ks13..15 LDS
//            (96KB); h_st DOUBLE-BUFFERED -> 1 barrier/step.
// WG 16..31: zscan role (R8 body, CHUNK=16).
// Block LDS = 128KB -> 1 WG/CU.
// =====================================================================
__global__ __launch_bounds__(256, 1) void scan_pipe_kernel(
    const f16* __restrict__ pk, const float* __restrict__ h0,
    const float* __restrict__ zq0, const float* __restrict__ chb,
    const float* __restrict__ cmb, const float* __restrict__ clb,
    const float* __restrict__ eps_comb, f16* __restrict__ xw,
    f16* __restrict__ z_all, f16* __restrict__ mu_all, f16* __restrict__ lv_all,
    unsigned* __restrict__ prog) {
  __shared__ __align__(16) f16 lds[65536];  // 128 KB union
  const int tid = threadIdx.x, lane = tid & 63, w = tid >> 6;
  const int colv = lane & 15, l4 = lane >> 4;

  if (blockIdx.x < 16) {
    // ------------------------- RNN role -------------------------
    const int g = blockIdx.x, b0 = g * 16;
    f16* whh_lds = lds;            // 49152 f16: ks 13..15 (frags 416..511)
    f16* h_db = lds + 49152;       // 2 x 8192 f16, swizzled [16][512]
    {
      const uint4* src = (const uint4*)(pk + PK_WHH + 212992u);  // frag 416*512
      for (int i = tid; i < 6144; i += 256) ((uint4*)whh_lds)[i] = src[i];
    }
    f16x8 whhA[8][13];
#pragma unroll
    for (int mt = 0; mt < 8; ++mt)
#pragma unroll
      for (int ks = 0; ks < 13; ++ks) {
        whhA[mt][ks] = *(const f16x8*)(pk + PK_WHH +
            ((size_t)(ks * 32 + w * 8 + mt) << 9) + (lane << 3));
        pin8(whhA[mt][ks]);
      }
    for (int i = tid; i < 8192; i += 256) h_db[swz(i >> 9, i & 511)] = (f16)h0[i & 511];
    __syncthreads();

    const int moff = w * 128 + l4 * 4;
    f16* xp = xw + (size_t)(b0 + colv) * RHD;
    f16x4 xwc[8], xwn[8];
#pragma unroll
    for (int mt = 0; mt < 8; ++mt) xwc[mt] = *(const f16x4*)(xp + moff + mt * 16);

    for (int c = 0; c < NCHNK; ++c) {
#pragma unroll 1
      for (int tt = 0; tt < CHUNK; ++tt) {
        int t = c * CHUNK + tt;
        f16* hr = h_db + (t & 1) * 8192;        // read buffer
        f16* hw = h_db + ((t & 1) ^ 1) * 8192;  // write buffer
        f16* xpn = (t < T_LEN - 1) ? xp + (size_t)BATCH * RHD : xp;
#pragma unroll
        for (int mt = 0; mt < 8; ++mt) xwn[mt] = *(const f16x4*)(xpn + moff + mt * 16);
        f32x4 acc[8]; zacc<8>(acc);
#pragma unroll
        for (int ks = 0; ks < 13; ++ks) {
          f16x8 B = *(const f16x8*)&hr[swz(colv, ks * 32 + l4 * 8)];
#pragma unroll
          for (int mt = 0; mt < 8; ++mt) acc[mt] = MFMA16(whhA[mt][ks], B, acc[mt]);
        }
#pragma unroll
        for (int ks = 0; ks < 3; ++ks) {
          f16x8 B = *(const f16x8*)&hr[swz(colv, (13 + ks) * 32 + l4 * 8)];
#pragma unroll
          for (int mt = 0; mt < 8; ++mt)
            acc[mt] = MFMA16(*(const f16x8*)(whh_lds +
                (((ks * 32 + w * 8 + mt) << 6) + lane) * 8), B, acc[mt]);
        }
#pragma unroll
        for (int mt = 0; mt < 8; ++mt) {
          f16x4 h4;
#pragma unroll
          for (int r = 0; r < 4; ++r)
            h4[r] = (f16)fmaxf(acc[mt][r] + (float)xwc[mt][r], 0.f);
          *(f16x4*)&hw[swz(colv, moff + mt * 16)] = h4;
          *(f16x4*)(xp + moff + mt * 16) = h4;  // h overwrites xw[t]
        }
        lbar();  // single barrier: hw writes visible before next step's reads
        xp = xpn;
#pragma unroll
        for (int mt = 0; mt < 8; ++mt) xwc[mt] = xwn[mt];
      }
      __syncthreads();  // drains all waves' vmem (h stores at L2)
      if (tid == 0)
        __hip_atomic_store(prog + g, (unsigned)(c + 1), __ATOMIC_RELEASE,
                           __HIP_MEMORY_SCOPE_AGENT);
    }
  } else {
    // ------------------------ zscan role (R8 body) ------------------------
    const int g = blockIdx.x - 16, b0 = g * 16;
    f16* cbml_lds = lds;           // 32768 f16 (ks 12..15)
    f16* hc_st = lds + 32768;      // 8192 f16, swizzled [16][512]
    f16* z_st  = lds + 40960;      // 2048 f16, swizzled [16][128]
    f16* m_st  = lds + 43008;      // [16][264] f16
    {
      const uint4* src = (const uint4*)(pk + PK_CBML + 98304u);
      for (int i = tid; i < 4096; i += 256) ((uint4*)cbml_lds)[i] = src[i];
    }
    f16x8 cbhA[8][4];
#pragma unroll
    for (int mt = 0; mt < 8; ++mt)
#pragma unroll
      for (int ks = 0; ks < 4; ++ks) {
        cbhA[mt][ks] = *(const f16x8*)(pk + PK_CBH +
            ((size_t)(ks * 32 + w * 8 + mt) << 9) + (lane << 3));
        pin8(cbhA[mt][ks]);
      }
    f16x8 cbmlA[4][12];
#pragma unroll
    for (int mt = 0; mt < 4; ++mt)
#pragma unroll
      for (int ks = 0; ks < 12; ++ks) {
        cbmlA[mt][ks] = *(const f16x8*)(pk + PK_CBML +
            ((size_t)(ks * 16 + w * 4 + mt) << 9) + (lane << 3));
        pin8(cbmlA[mt][ks]);
      }
    f16x4 chbv[8];
#pragma unroll
    for (int mt = 0; mt < 8; ++mt)
#pragma unroll
      for (int r = 0; r < 4; ++r)
        chbv[mt][r] = (f16)chb[(w * 8 + mt) * 16 + l4 * 4 + r];
    float mb[4][4];
#pragma unroll
    for (int mt = 0; mt < 4; ++mt)
#pragma unroll
      for (int r = 0; r < 4; ++r) {
        int d = (w * 4 + mt) * 16 + l4 * 4 + r;
        mb[mt][r] = (d < 128) ? cmb[d] : clb[d - 128];
      }
    for (int i = tid; i < 2048; i += 256) {
      f16 zv = (f16)zq0[i & 127];
      z_st[swz128(i >> 7, i & 127)] = zv;
      z_all[(size_t)(b0 + (i >> 7)) * ZDIM + (i & 127)] = zv;  // z_all[0]
    }
    __syncthreads();

    const int moff = w * 128 + l4 * 4;   // hc dims (M=512)
    const int m2off = w * 64 + l4 * 4;   // mu|lv dims (M=256)
    const int be = tid >> 4, d0 = (tid & 15) * 8;
    const f16* hp = xw + (size_t)(b0 + colv) * RHD;
    const float* epb = eps_comb + (size_t)(b0 + be) * ZDIM + d0;
    f16x4 hv[8];
    float4 ep0, ep1, epn0, epn1;

    for (int c = 0; c < NCHNK; ++c) {
      if (tid == 0) {
        while (ldflag(prog + g) < (unsigned)(c + 1)) __builtin_amdgcn_s_sleep(2);
      }
      __syncthreads();
      __builtin_amdgcn_fence(__ATOMIC_ACQUIRE, "agent");
      {
        const f16* hpt = hp + (size_t)(c * CHUNK) * BATCH * RHD;
#pragma unroll
        for (int mt = 0; mt < 8; ++mt) hv[mt] = *(const f16x4*)(hpt + moff + mt * 16);
        const float* ept = epb + (size_t)(c * CHUNK) * BATCH * ZDIM;
        ep0 = *(const float4*)ept; ep1 = *(const float4*)(ept + 4);
      }
#pragma unroll 1
      for (int tt = 0; tt < CHUNK; ++tt) {
        int t = c * CHUNK + tt;
        // GEMM1: cbh @ z (M=512, K=128)
        f16x8 zB[4];
#pragma unroll
        for (int ks = 0; ks < 4; ++ks)
          zB[ks] = *(const f16x8*)&z_st[swz128(colv, ks * 32 + l4 * 8)];
        f32x4 a1[8]; zacc<8>(a1);
#pragma unroll
        for (int ks = 0; ks < 4; ++ks)
#pragma unroll
          for (int mt = 0; mt < 8; ++mt) a1[mt] = MFMA16(cbhA[mt][ks], zB[ks], a1[mt]);
#pragma unroll
        for (int mt = 0; mt < 8; ++mt) {
          f16x4 hc4;
#pragma unroll
          for (int r = 0; r < 4; ++r) {
            float cs = a1[mt][r] + (float)chbv[mt][r];
            float ex = __builtin_amdgcn_exp2f(cs * 2.885390082f);   // e^(2x)
            float th = 1.f - 2.f * __builtin_amdgcn_rcpf(ex + 1.f); // tanh
            hc4[r] = (f16)(0.5f * (th + (float)hv[mt][r]));
          }
          *(f16x4*)&hc_st[swz(colv, moff + mt * 16)] = hc4;
        }
        lbar();  // B1: hc ready
        if (tt < CHUNK - 1) {
          const f16* hpt = hp + (size_t)(t + 1) * BATCH * RHD;
#pragma unroll
          for (int mt = 0; mt < 8; ++mt) hv[mt] = *(const f16x4*)(hpt + moff + mt * 16);
          const float* ept = epb + (size_t)(t + 1) * BATCH * ZDIM;
          epn0 = *(const float4*)ept; epn1 = *(const float4*)(ept + 4);
        }
        // GEMM2: cbml @ hc (M=256, K=512)
        f32x4 a2[4]; zacc<4>(a2);
#pragma unroll
        for (int ks = 0; ks < 12; ++ks) {
          f16x8 hcB = *(const f16x8*)&hc_st[swz(colv, ks * 32 + l4 * 8)];
#pragma unroll
          for (int mt = 0; mt < 4; ++mt) a2[mt] = MFMA16(cbmlA[mt][ks], hcB, a2[mt]);
        }
#pragma unroll
        for (int ks = 0; ks < 4; ++ks) {
          f16x8 hcB = *(const f16x8*)&hc_st[swz(colv, (12 + ks) * 32 + l4 * 8)];
#pragma unroll
          for (int mt = 0; mt < 4; ++mt)
            a2[mt] = MFMA16(*(const f16x8*)(cbml_lds +
                (((ks * 16 + w * 4 + mt) << 6) + lane) * 8), hcB, a2[mt]);
        }
#pragma unroll
        for (int mt = 0; mt < 4; ++mt) {
          f16x4 v;
#pragma unroll
          for (int r = 0; r < 4; ++r) v[r] = (f16)(a2[mt][r] + mb[mt][r]);  // biased
          *(f16x4*)&m_st[colv * 264 + m2off + mt * 16] = v;
        }
        lbar();  // B2: mu|lv ready
        {
          f16x8 mu8 = *(const f16x8*)&m_st[be * 264 + d0];
          f16x8 lv8 = *(const f16x8*)&m_st[be * 264 + 128 + d0];
          float epv[8] = {ep0.x, ep0.y, ep0.z, ep0.w, ep1.x, ep1.y, ep1.z, ep1.w};
          f16x8 z8;
#pragma unroll
          for (int r = 0; r < 8; ++r) {
            float mu = (float)mu8[r], lv = (float)lv8[r];
            z8[r] = (f16)(mu + epv[r] * __builtin_amdgcn_exp2f(lv * 0.7213475204f));
          }
          *(f16x8*)&z_st[swz128(be, d0)] = z8;
          size_t o = ((size_t)t * BATCH + b0 + be) * ZDIM + d0;
          *(f16x8*)(z_all + o + (size_t)BATCH * ZDIM) = z8;  // slot t+1
          *(f16x8*)(mu_all + o) = mu8;
          *(f16x8*)(lv_all + o) = lv8;
        }
        lbar();  // B3: z_st/m_st safe
        ep0 = epn0; ep1 = epn1;
      }
    }
  }
}

// =====================================================================
// Phase D: parallel transition/emitter/losses over all (t,b). (R8 form)
// =====================================================================
__global__ __launch_bounds__(256) void dpar_kernel(
    const f16* __restrict__ z_all, const f16* __restrict__ mu_all,
    const f16* __restrict__ lv_all, const float* __restrict__ y,
    const float* __restrict__ eps_emit, const f16* __restrict__ pk,
    const float* __restrict__ g1b, const float* __restrict__ g2b,
    const float* __restrict__ p1b, const float* __restrict__ p2b,
    const float* __restrict__ tmub, const float* __restrict__ tlvb,
    const float* __restrict__ e1b, const float* __restrict__ e2b,
    const float* __restrict__ emub, const float* __restrict__ em_logvar,
    float* __restrict__ partials) {
  __shared__ __align__(16) f16 sb256[4][16 * 264];
  __shared__ __align__(16) f16 sb128[4][16 * 136];
  __shared__ float wsum[4][2];
  const int tid = threadIdx.x, lane = tid & 63, w = tid >> 6;
  const int colv = lane & 15, rb = (lane >> 4) << 2;
  const int m0 = blockIdx.x * 64 + w * 16;
  const int t = m0 >> 8, b0 = m0 & 255;
  f16* B256 = &sb256[w][0];
  f16* B128 = &sb128[w][0];

  f16x8 zp[4], zt[4];
  const f16* zpr = z_all + ((size_t)t * BATCH + b0) * ZDIM;
#pragma unroll
  for (int ks = 0; ks < 4; ++ks) {
    zp[ks] = *(const f16x8*)(zpr + (size_t)colv * ZDIM + ks * 32 + ((lane >> 4) << 3));
    zt[ks] = *(const f16x8*)(zpr + (size_t)BATCH * ZDIM + (size_t)colv * ZDIM + ks * 32 + ((lane >> 4) << 3));
  }

  f32x4 a16[16], a8[8];
  f16x8 af[8], af4[4];
  zacc<16>(a16); gemm_regA<4, 16>(zp, pk + PK_G1, lane, a16);
  store_relu<16>(a16, g1b, B256, 264, lane); ldsfence();
  load_af<8>(B256, 264, lane, af); ldsfence();
  zacc<8>(a8); gemm_regA<8, 8>(af, pk + PK_G2, lane, a8);
  f32x4 gate[8];
#pragma unroll
  for (int j = 0; j < 8; ++j)
#pragma unroll
    for (int r = 0; r < 4; ++r)
      gate[j][r] = 1.f / (1.f + expf(-(a8[j][r] + g2b[j * 16 + colv])));
  zacc<16>(a16); gemm_regA<4, 16>(zp, pk + PK_P1, lane, a16);
  store_relu<16>(a16, p1b, B256, 264, lane); ldsfence();
  load_af<8>(B256, 264, lane, af); ldsfence();
  zacc<8>(a8); gemm_regA<8, 8>(af, pk + PK_P2, lane, a8);
  f32x4 prop[8];
#pragma unroll
  for (int j = 0; j < 8; ++j)
#pragma unroll
    for (int r = 0; r < 4; ++r) {
      float v = a8[j][r] + p2b[j * 16 + colv];
      prop[j][r] = v;
      B128[(rb + r) * 136 + j * 16 + colv] = (f16)fmaxf(v, 0.f);
    }
  ldsfence();
  zacc<8>(a8); gemm_regA<4, 8>(zp, pk + PK_TMU, lane, a8);
  f32x4 prmu[8];
#pragma unroll
  for (int j = 0; j < 8; ++j)
#pragma unroll
    for (int r = 0; r < 4; ++r) {
      float gg = gate[j][r];
      prmu[j][r] = (1.f - gg) * (a8[j][r] + tmub[j * 16 + colv]) + gg * prop[j][r];
    }
  load_af<4>(B128, 136, lane, af4); ldsfence();
  zacc<8>(a8); gemm_regA<4, 8>(af4, pk + PK_TLV, lane, a8);
  f32x4 prlv[8];
#pragma unroll
  for (int j = 0; j < 8; ++j)
#pragma unroll
    for (int r = 0; r < 4; ++r) prlv[j][r] = a8[j][r] + tlvb[j * 16 + colv];
  zacc<16>(a16); gemm_regA<4, 16>(zt, pk + PK_E1, lane, a16);
  store_relu<16>(a16, e1b, B256, 264, lane); ldsfence();
  load_af<8>(B256, 264, lane, af); ldsfence();
  zacc<16>(a16); gemm_regA<8, 16>(af, pk + PK_E2, lane, a16);
  store_relu<16>(a16, e2b, B256, 264, lane); ldsfence();
  load_af<8>(B256, 264, lane, af); ldsfence();
  zacc<8>(a8); gemm_regA<8, 8>(af, pk + PK_EMU, lane, a8);
  float srec = 0.f, skl = 0.f;
#pragma unroll
  for (int j = 0; j < 8; ++j)
#pragma unroll
    for (int r = 0; r < 4; ++r) {
      int row = rb + r, n = j * 16 + colv;
      size_t tb = (size_t)t * BATCH + b0 + row;
      float xt = a8[j][r] + emub[n] + eps_emit[tb * DIMX + n] * expf(0.5f * em_logvar[n]);
      float dy = xt - y[((size_t)(b0 + row) * T_LEN + t) * DIMX + n];
      srec += dy * dy;
      float m_ = (float)mu_all[tb * ZDIM + n], l_ = (float)lv_all[tb * ZDIM + n];
      float dm = m_ - prmu[j][r];
      skl += 0.5f * (prlv[j][r] - l_ + (expf(l_) + dm * dm) * expf(-prlv[j][r]) - 1.f);
    }
#pragma unroll
  for (int off = 32; off; off >>= 1) {
    srec += __shfl_xor(srec, off);
    skl += __shfl_xor(skl, off);
  }
  if (lane == 0) { wsum[w][0] = srec; wsum[w][1] = skl; }
  __syncthreads();
  if (tid == 0) {
    partials[blockIdx.x * 2 + 0] = wsum[0][0] + wsum[1][0] + wsum[2][0] + wsum[3][0];
    partials[blockIdx.x * 2 + 1] = wsum[0][1] + wsum[1][1] + wsum[2][1] + wsum[3][1];
  }
}

// =====================================================================
__global__ void finalize_kernel(const float* __restrict__ partials, float* __restrict__ out) {
  __shared__ float sm[256][2];
  int tid = threadIdx.x;
  float r = 0.f, kk = 0.f;
  for (int i = tid; i < 2048; i += 256) {
    r += partials[2 * i];
    kk += partials[2 * i + 1];
  }
  sm[tid][0] = r; sm[tid][1] = kk;
  __syncthreads();
  for (int off = 128; off; off >>= 1) {
    if (tid < off) { sm[tid][0] += sm[tid + off][0]; sm[tid][1] += sm[tid + off][1]; }
    __syncthreads();
  }
  if (tid == 0) {
    out[0] = sm[0][0] / (131072.f * 128.f);
    out[1] = sm[0][1] / 131072.f;
  }
}

// =====================================================================
extern "C" void kernel_launch(void* const* d_in, const int* in_sizes, int n_in,
                              void* d_out, int out_size, void* d_ws, size_t ws_size,
                              hipStream_t stream) {
  (void)in_sizes; (void)n_in; (void)out_size;
  const float* x        = (const float*)d_in[0];
  const float* y        = (const float*)d_in[1];
  const float* eps_comb = (const float*)d_in[2];
  const float* eps_emit = (const float*)d_in[3];
  const float* wih = (const float*)d_in[4];
  const float* whh = (const float*)d_in[5];
  const float* bih = (const float*)d_in[6];
  const float* bhh = (const float*)d_in[7];
  const float* h0  = (const float*)d_in[8];
  const float* zq0 = (const float*)d_in[9];
  const float* g1W = (const float*)d_in[10]; const float* g1b = (const float*)d_in[11];
  const float* g2W = (const float*)d_in[12]; const float* g2b = (const float*)d_in[13];
  const float* p1W = (const float*)d_in[14]; const float* p1b = (const float*)d_in[15];
  const float* p2W = (const float*)d_in[16]; const float* p2b = (const float*)d_in[17];
  const float* tmuW = (const float*)d_in[18]; const float* tmub = (const float*)d_in[19];
  const float* tlvW = (const float*)d_in[20]; const float* tlvb = (const float*)d_in[21];
  const float* chW = (const float*)d_in[22]; const float* chb = (const float*)d_in[23];
  const float* cmW = (const float*)d_in[24]; const float* cmb = (const float*)d_in[25];
  const float* clW = (const float*)d_in[26]; const float* clb = (const float*)d_in[27];
  const float* e1W = (const float*)d_in[28]; const float* e1b = (const float*)d_in[29];
  const float* e2W = (const float*)d_in[30]; const float* e2b = (const float*)d_in[31];
  const float* emW = (const float*)d_in[32]; const float* emb = (const float*)d_in[33];
  const float* elv = (const float*)d_in[34];

  char* ws = (char*)d_ws;
  f16*  xw      = (f16*)(ws + WS_XW);
  f16*  z_all   = (f16*)(ws + WS_Z);
  f16*  mu_all  = (f16*)(ws + WS_MU);
  f16*  lv_all  = (f16*)(ws + WS_LV);
  f16*  pk      = (f16*)(ws + WS_PK);
  float* partials = (float*)(ws + WS_PART);
  unsigned* prog  = (unsigned*)(ws + WS_PROG);
  float* out = (float*)d_out;
  if (ws_size < WS_END) return;

  zero_prog_kernel<<<dim3(1), dim3(64), 0, stream>>>(prog);

  PackTab tb;
  unsigned wg = 0; int ei = 0;
#define PACK(S1, S2, NS_, K_, N_, OFF) \
  tb.e[ei] = PackEnt{S1, S2, NS_, K_, N_, OFF, wg}; wg += (unsigned)((K_) * (N_)) / 256; ++ei;
  PACK(wih, wih, 512, 128, 512, PK_WIH);
  PACK(whh, whh, 512, 512, 512, PK_WHH);
  PACK(g1W, g1W, 256, 128, 256, PK_G1);
  PACK(g2W, g2W, 128, 256, 128, PK_G2);
  PACK(p1W, p1W, 256, 128, 256, PK_P1);
  PACK(p2W, p2W, 128, 256, 128, PK_P2);
  PACK(tmuW, tmuW, 128, 128, 128, PK_TMU);
  PACK(tlvW, tlvW, 128, 128, 128, PK_TLV);
  PACK(chW, chW, 512, 128, 512, PK_CBH);
  PACK(cmW, clW, 128, 512, 256, PK_CBML);
  PACK(e1W, e1W, 256, 128, 256, PK_E1);
  PACK(e2W, e2W, 256, 256, 256, PK_E2);
  PACK(emW, emW, 128, 256, 128, PK_EMU);
#undef PACK
  pack_all_kernel<<<dim3(wg), dim3(256), 0, stream>>>(tb, pk);

  xw_kernel<<<dim3(256), dim3(256), 0, stream>>>(x, pk, bih, bhh, xw);
  scan_pipe_kernel<<<dim3(32), dim3(256), 0, stream>>>(
      pk, h0, zq0, chb, cmb, clb, eps_comb, xw, z_all, mu_all, lv_all, prog);
  dpar_kernel<<<dim3(2048), dim3(256), 0, stream>>>(z_all, mu_all, lv_all, y, eps_emit, pk,
                                                    g1b, g2b, p1b, p2b, tmub, tlvb, e1b, e2b,
                                                    emb, elv, partials);
  finalize_kernel<<<dim3(1), dim3(256), 0, stream>>>(partials, out);
}

// Round 16
// 2521.530 us; speedup vs baseline: 1.1220x; 1.1190x over previous
//
#include <hip/hip_runtime.h>

// Deep Kalman Filter inference, MI355X/gfx950.  (R8 configuration — the
// verified best at 2522us; R9-R15 variations all regressed and were
// reverted. See ledger in commit history.)
// pack_all, xw = x@Wih+bias (2048 WG), scan_pipe (32 WG: 16 rnn-role +
// 16 zscan-role, chunked one-way flag sync, 256 thr), dpar (2048 WG),
// finalize.
// R2: fine-grained cross-WG sync ~6.6us each -> coarse 32-step chunks.
// R3: on-chip weight budget = regfile + 160KB LDS per CU.
// R4/R5: pin weights via asm to stop remat; prefetch inputs.
// R8: arch "v" regs cap at 256; 12-reg+4-LDS Whh split fits exactly.
// R9: concurrent bulk traffic stretches the scan -> xw serial before it.
// R10: dpar needs occupancy -> separate kernel. R11: staged m_st epilogue
// (store coalescing). R13: no third branch (shared regalloc). R15: >256
// "v" requests spill into AGPR-shuffle overhead -> keep 12-reg split.

#define T_LEN 512
#define BATCH 256
#define DIMX  128
#define ZDIM  128
#define RHD   512
#define CHUNK 32

typedef _Float16 f16;
typedef _Float16 f16x4 __attribute__((ext_vector_type(4)));
typedef _Float16 f16x8 __attribute__((ext_vector_type(8)));
typedef float    f32x4 __attribute__((ext_vector_type(4)));

#define MFMA16(a,b,c) __builtin_amdgcn_mfma_f32_16x16x32_f16((a),(b),(c),0,0,0)

// ---- packed weight element offsets (f16 elements) ----
#define PK_WIH  0u
#define PK_WHH  65536u
#define PK_G1   327680u
#define PK_G2   360448u
#define PK_P1   393216u
#define PK_P2   425984u
#define PK_TMU  458752u
#define PK_TLV  475136u
#define PK_CBH  491520u
#define PK_CBML 557056u
#define PK_E1   688128u
#define PK_E2   720896u
#define PK_EMU  786432u

// ---- workspace byte offsets ----
#define WS_XW   0ull                          // f16 [T][B][RH]: xw in, h out (aliased)
#define WS_Z    (WS_XW  + 134217728ull)       // f16 [T+1][B][Z]
#define WS_MU   (WS_Z   + 33619968ull)        // f16 [T][B][Z]
#define WS_LV   (WS_MU  + 33554432ull)        // f16 [T][B][Z]
#define WS_PK   (WS_LV  + 33554432ull)        // f16 packed weights
#define WS_PART (WS_PK  + 1638400ull)         // f32 [2048][2]
#define WS_PROG (WS_PART + 16384ull)          // u32 prog[16]
#define WS_END  (WS_PROG + 256ull)

// =====================================================================
// helpers
// =====================================================================
__device__ __forceinline__ void ldsfence() {
  asm volatile("s_waitcnt lgkmcnt(0)" ::: "memory");
  __builtin_amdgcn_sched_barrier(0);
}

// lgkm-only workgroup barrier (global ops stay in flight).
__device__ __forceinline__ void lbar() {
  asm volatile("s_waitcnt lgkmcnt(0)" ::: "memory");
  __builtin_amdgcn_s_barrier();
  asm volatile("" ::: "memory");
}

// Anti-rematerialization pin.
__device__ __forceinline__ void pin8(f16x8& v) {
  f32x4 t = __builtin_bit_cast(f32x4, v);
  asm volatile("" : "+v"(t));
  v = __builtin_bit_cast(f16x8, t);
}

template<int N>
__device__ __forceinline__ void zacc(f32x4* a) {
  f32x4 z = {0.f, 0.f, 0.f, 0.f};
#pragma unroll
  for (int i = 0; i < N; ++i) a[i] = z;
}

__device__ __forceinline__ f16x8 cvt8(const float* p) {
  float4 a = *(const float4*)p, b = *(const float4*)(p + 4);
  f16x8 r;
  r[0] = (f16)a.x; r[1] = (f16)a.y; r[2] = (f16)a.z; r[3] = (f16)a.w;
  r[4] = (f16)b.x; r[5] = (f16)b.y; r[6] = (f16)b.z; r[7] = (f16)b.w;
  return r;
}

// XOR swizzle: 16B-chunk of row r at f16-col c -> c ^ ((r&7)<<3)
__device__ __forceinline__ int swz(int row, int col) {
  return (row << 9) + (col ^ ((row & 7) << 3));     // stride 512 f16
}
__device__ __forceinline__ int swz128(int row, int col) {
  return (row << 7) + (col ^ ((row & 7) << 3));     // stride 128 f16
}

// (dpar helpers)
template<int KS>
__device__ __forceinline__ void load_af(const f16* src, int sstr, int lane, f16x8* af) {
#pragma unroll
  for (int ks = 0; ks < KS; ++ks)
    af[ks] = *(const f16x8*)(src + (lane & 15) * sstr + ks * 32 + ((lane >> 4) << 3));
}

template<int KS, int NT>
__device__ __forceinline__ void gemm_regA(const f16x8* af, const f16* __restrict__ bp,
                                          int lane, f32x4* acc) {
#pragma unroll
  for (int ks = 0; ks < KS; ++ks)
#pragma unroll
    for (int j = 0; j < NT; ++j) {
      f16x8 bf = *(const f16x8*)(bp + (((size_t)(ks * NT + j)) << 9) + (lane << 3));
      acc[j] = MFMA16(af[ks], bf, acc[j]);
    }
}

template<int NT>
__device__ __forceinline__ void store_relu(const f32x4* acc, const float* __restrict__ bias,
                                           f16* dst, int dstr, int lane) {
  int colv = lane & 15, rb = (lane >> 4) << 2;
#pragma unroll
  for (int j = 0; j < NT; ++j)
#pragma unroll
    for (int r = 0; r < 4; ++r)
      dst[(rb + r) * dstr + j * 16 + colv] = (f16)fmaxf(acc[j][r] + bias[j * 16 + colv], 0.f);
}

__device__ __forceinline__ unsigned ldflag(const unsigned* p) {
  return __hip_atomic_load(p, __ATOMIC_RELAXED, __HIP_MEMORY_SCOPE_AGENT);
}

// =====================================================================
// pack_all: all 13 matrices. W[K][N] fp32 -> fp16 frags (fi = ks*(N/16)+nt)
// =====================================================================
struct PackEnt { const float* s1; const float* s2; int nsplit, K, N; unsigned dst, wg0; };
struct PackTab { PackEnt e[13]; };

__global__ void pack_all_kernel(PackTab tb, f16* __restrict__ pk) {
  int i = 0;
#pragma unroll
  for (int k = 1; k < 13; ++k)
    if (blockIdx.x >= tb.e[k].wg0) i = k;
  const PackEnt& E = tb.e[i];
  int idx = (blockIdx.x - E.wg0) * 256 + threadIdx.x;
  if (idx >= E.K * E.N) return;
  int j = idx & 7, l = (idx >> 3) & 63, fi = idx >> 9;
  int NTt = E.N >> 4;
  int nt = fi % NTt, ks = fi / NTt;
  int k = ks * 32 + ((l >> 4) << 3) + j;
  int n = (nt << 4) + (l & 15);
  float v;
  if (n < E.nsplit) v = E.s1[(size_t)k * E.nsplit + n];
  else              v = E.s2[(size_t)k * (E.N - E.nsplit) + (n - E.nsplit)];
  pk[E.dst + idx] = (f16)v;
}

__global__ void zero_prog_kernel(unsigned* __restrict__ p) {
  if (threadIdx.x < 64)
    __hip_atomic_store(p + threadIdx.x, 0u, __ATOMIC_RELAXED, __HIP_MEMORY_SCOPE_AGENT);
}

// =====================================================================
// xw = x @ Wih + (bih + bhh), f16 out. 2048 WG x 256 thr. (serial)
// =====================================================================
__global__ __launch_bounds__(256) void xw_kernel(
    const float* __restrict__ x, const f16* __restrict__ pk,
    const float* __restrict__ bih, const float* __restrict__ bhh,
    f16* __restrict__ xw) {
  __shared__ float bs[512];
  const int tid = threadIdx.x, lane = tid & 63, w = tid >> 6;
  const int colv = lane & 15, l4 = lane >> 4;
  const int m0 = blockIdx.x * 64 + w * 16;
  const int t = m0 >> 8, b0 = m0 & 255;
  for (int i = tid; i < 512; i += 256) bs[i] = bih[i] + bhh[i];
  __syncthreads();
  f16x8 xB[4];
  const float* xr = x + ((size_t)(b0 + colv) * T_LEN + t) * DIMX;
#pragma unroll
  for (int ks = 0; ks < 4; ++ks) xB[ks] = cvt8(xr + ks * 32 + l4 * 8);
  f32x4 acc[32]; zacc<32>(acc);
#pragma unroll
  for (int ks = 0; ks < 4; ++ks)
#pragma unroll
    for (int mt = 0; mt < 32; ++mt)
      acc[mt] = MFMA16(*(const f16x8*)(pk + PK_WIH + ((size_t)(ks * 32 + mt) << 9) + (lane << 3)),
                       xB[ks], acc[mt]);
  f16* xo = xw + ((size_t)t * BATCH + b0 + colv) * RHD;
#pragma unroll
  for (int mt = 0; mt < 32; ++mt) {
    f16x4 v;
#pragma unroll
    for (int r = 0; r < 4; ++r) v[r] = (f16)(acc[mt][r] + bs[mt * 16 + l4 * 4 + r]);
    *(f16x4*)(xo + mt * 16 + l4 * 4) = v;
  }
}

// =====================================================================
// scan_pipe: 32 WGs x 256 thr (4 waves, 1 WG/CU via 144KB LDS).
// WG 0..15:  rnn role, group g: Whh ks0..11 pinned regs, ks12..15 LDS
//            (128KB). Releases prog[g] per 32-step chunk.
// WG 16..31: zscan role, group g: cbh regs, cbml ks0..11 regs + 64KB LDS.
//            Acquire-spin on prog[g].
// =====================================================================
__global__ __launch_bounds__(256, 1) void scan_pipe_kernel(
    const f16* __restrict__ pk, const float* __restrict__ h0,
    const float* __restrict__ zq0, const float* __restrict__ chb,
    const float* __restrict__ cmb, const float* __restrict__ clb,
    const float* __restrict__ eps_comb, f16* __restrict__ xw,
    f16* __restrict__ z_all, f16* __restrict__ mu_all, f16* __restrict__ lv_all,
    unsigned* __restrict__ prog) {
  __shared__ __align__(16) f16 lds[73728];  // 144 KB union
  const int tid = threadIdx.x, lane = tid & 63, w = tid >> 6;
  const int colv = lane & 15, l4 = lane >> 4;

  if (blockIdx.x < 16) {
    // ------------------------- RNN role -------------------------
    const int g = blockIdx.x, b0 = g * 16;
    f16* whh_lds = lds;          // 65536 f16 (ks 12..15)
    f16* h_st = lds + 65536;     // 8192 f16, swizzled [16][512]
    {
      const uint4* src = (const uint4*)(pk + PK_WHH + 196608u);
      for (int i = tid; i < 8192; i += 256) ((uint4*)whh_lds)[i] = src[i];
    }
    f16x8 whhA[8][12];
#pragma unroll
    for (int mt = 0; mt < 8; ++mt)
#pragma unroll
      for (int ks = 0; ks < 12; ++ks) {
        whhA[mt][ks] = *(const f16x8*)(pk + PK_WHH +
            ((size_t)(ks * 32 + w * 8 + mt) << 9) + (lane << 3));
        pin8(whhA[mt][ks]);
      }
    for (int i = tid; i < 8192; i += 256) h_st[swz(i >> 9, i & 511)] = (f16)h0[i & 511];
    __syncthreads();

    const int moff = w * 128 + l4 * 4;
    f16* xp = xw + (size_t)(b0 + colv) * RHD;
    f16x4 xwc[8], xwn[8];
#pragma unroll
    for (int mt = 0; mt < 8; ++mt) xwc[mt] = *(const f16x4*)(xp + moff + mt * 16);

    for (int c = 0; c < T_LEN / CHUNK; ++c) {
#pragma unroll 1
      for (int tt = 0; tt < CHUNK; ++tt) {
        int t = c * CHUNK + tt;
        f16* xpn = (t < T_LEN - 1) ? xp + (size_t)BATCH * RHD : xp;
#pragma unroll
        for (int mt = 0; mt < 8; ++mt) xwn[mt] = *(const f16x4*)(xpn + moff + mt * 16);
        f32x4 acc[8]; zacc<8>(acc);
#pragma unroll
        for (int ks = 0; ks < 12; ++ks) {
          f16x8 B = *(const f16x8*)&h_st[swz(colv, ks * 32 + l4 * 8)];
#pragma unroll
          for (int mt = 0; mt < 8; ++mt) acc[mt] = MFMA16(whhA[mt][ks], B, acc[mt]);
        }
#pragma unroll
        for (int ks = 0; ks < 4; ++ks) {
          f16x8 B = *(const f16x8*)&h_st[swz(colv, (12 + ks) * 32 + l4 * 8)];
#pragma unroll
          for (int mt = 0; mt < 8; ++mt)
            acc[mt] = MFMA16(*(const f16x8*)(whh_lds +
                (((ks * 32 + w * 8 + mt) << 6) + lane) * 8), B, acc[mt]);
        }
        lbar();  // B1: h_st reads done
#pragma unroll
        for (int mt = 0; mt < 8; ++mt) {
          f16x4 h4;
#pragma unroll
          for (int r = 0; r < 4; ++r)
            h4[r] = (f16)fmaxf(acc[mt][r] + (float)xwc[mt][r], 0.f);
          *(f16x4*)&h_st[swz(colv, moff + mt * 16)] = h4;
          *(f16x4*)(xp + moff + mt * 16) = h4;  // h overwrites xw[t]
        }
        lbar();  // B2
        xp = xpn;
#pragma unroll
        for (int mt = 0; mt < 8; ++mt) xwc[mt] = xwn[mt];
      }
      __syncthreads();  // drains all waves' vmem (h stores at L2)
      if (tid == 0)
        __hip_atomic_store(prog + g, (unsigned)(c + 1), __ATOMIC_RELEASE,
                           __HIP_MEMORY_SCOPE_AGENT);
    }
  } else {
    // ------------------------ zscan role ------------------------
    const int g = blockIdx.x - 16, b0 = g * 16;
    f16* cbml_lds = lds;           // 32768 f16 (ks 12..15)
    f16* hc_st = lds + 32768;      // 8192 f16, swizzled [16][512]
    f16* z_st  = lds + 40960;      // 2048 f16, swizzled [16][128]
    f16* m_st  = lds + 43008;      // [16][264] f16
    {
      const uint4* src = (const uint4*)(pk + PK_CBML + 98304u);
      for (int i = tid; i < 4096; i += 256) ((uint4*)cbml_lds)[i] = src[i];
    }
    f16x8 cbhA[8][4];
#pragma unroll
    for (int mt = 0; mt < 8; ++mt)
#pragma unroll
      for (int ks = 0; ks < 4; ++ks) {
        cbhA[mt][ks] = *(const f16x8*)(pk + PK_CBH +
            ((size_t)(ks * 32 + w * 8 + mt) << 9) + (lane << 3));
        pin8(cbhA[mt][ks]);
      }
    f16x8 cbmlA[4][12];
#pragma unroll
    for (int mt = 0; mt < 4; ++mt)
#pragma unroll
      for (int ks = 0; ks < 12; ++ks) {
        cbmlA[mt][ks] = *(const f16x8*)(pk + PK_CBML +
            ((size_t)(ks * 16 + w * 4 + mt) << 9) + (lane << 3));
        pin8(cbmlA[mt][ks]);
      }
    f16x4 chbv[8];
#pragma unroll
    for (int mt = 0; mt < 8; ++mt)
#pragma unroll
      for (int r = 0; r < 4; ++r)
        chbv[mt][r] = (f16)chb[(w * 8 + mt) * 16 + l4 * 4 + r];
    float mb[4][4];
#pragma unroll
    for (int mt = 0; mt < 4; ++mt)
#pragma unroll
      for (int r = 0; r < 4; ++r) {
        int d = (w * 4 + mt) * 16 + l4 * 4 + r;
        mb[mt][r] = (d < 128) ? cmb[d] : clb[d - 128];
      }
    for (int i = tid; i < 2048; i += 256) {
      f16 zv = (f16)zq0[i & 127];
      z_st[swz128(i >> 7, i & 127)] = zv;
      z_all[(size_t)(b0 + (i >> 7)) * ZDIM + (i & 127)] = zv;  // z_all[0]
    }
    __syncthreads();

    const int moff = w * 128 + l4 * 4;   // hc dims (M=512)
    const int m2off = w * 64 + l4 * 4;   // mu|lv dims (M=256)
    const int be = tid >> 4, d0 = (tid & 15) * 8;
    const f16* hp = xw + (size_t)(b0 + colv) * RHD;
    const float* epb = eps_comb + (size_t)(b0 + be) * ZDIM + d0;
    f16x4 hv[8];
    float4 ep0, ep1, epn0, epn1;

    for (int c = 0; c < T_LEN / CHUNK; ++c) {
      if (tid == 0) {
        while (ldflag(prog + g) < (unsigned)(c + 1)) __builtin_amdgcn_s_sleep(2);
      }
      __syncthreads();
      __builtin_amdgcn_fence(__ATOMIC_ACQUIRE, "agent");
      {
        const f16* hpt = hp + (size_t)(c * CHUNK) * BATCH * RHD;
#pragma unroll
        for (int mt = 0; mt < 8; ++mt) hv[mt] = *(const f16x4*)(hpt + moff + mt * 16);
        const float* ept = epb + (size_t)(c * CHUNK) * BATCH * ZDIM;
        ep0 = *(const float4*)ept; ep1 = *(const float4*)(ept + 4);
      }
#pragma unroll 1
      for (int tt = 0; tt < CHUNK; ++tt) {
        int t = c * CHUNK + tt;
        // GEMM1: cbh @ z (M=512, K=128)
        f16x8 zB[4];
#pragma unroll
        for (int ks = 0; ks < 4; ++ks)
          zB[ks] = *(const f16x8*)&z_st[swz128(colv, ks * 32 + l4 * 8)];
        f32x4 a1[8]; zacc<8>(a1);
#pragma unroll
        for (int ks = 0; ks < 4; ++ks)
#pragma unroll
          for (int mt = 0; mt < 8; ++mt) a1[mt] = MFMA16(cbhA[mt][ks], zB[ks], a1[mt]);
#pragma unroll
        for (int mt = 0; mt < 8; ++mt) {
          f16x4 hc4;
#pragma unroll
          for (int r = 0; r < 4; ++r) {
            float cs = a1[mt][r] + (float)chbv[mt][r];
            float ex = __builtin_amdgcn_exp2f(cs * 2.885390082f);   // e^(2x)
            float th = 1.f - 2.f * __builtin_amdgcn_rcpf(ex + 1.f); // tanh
            hc4[r] = (f16)(0.5f * (th + (float)hv[mt][r]));
          }
          *(f16x4*)&hc_st[swz(colv, moff + mt * 16)] = hc4;
        }
        lbar();  // B1: hc ready
        if (tt < CHUNK - 1) {
          const f16* hpt = hp + (size_t)(t + 1) * BATCH * RHD;
#pragma unroll
          for (int mt = 0; mt < 8; ++mt) hv[mt] = *(const f16x4*)(hpt + moff + mt * 16);
          const float* ept = epb + (size_t)(t + 1) * BATCH * ZDIM;
          epn0 = *(const float4*)ept; epn1 = *(const float4*)(ept + 4);
        }
        // GEMM2: cbml @ hc (M=256, K=512)
        f32x4 a2[4]; zacc<4>(a2);
#pragma unroll
        for (int ks = 0; ks < 12; ++ks) {
          f16x8 hcB = *(const f16x8*)&hc_st[swz(colv, ks * 32 + l4 * 8)];
#pragma unroll
          for (int mt = 0; mt < 4; ++mt) a2[mt] = MFMA16(cbmlA[mt][ks], hcB, a2[mt]);
        }
#pragma unroll
        for (int ks = 0; ks < 4; ++ks) {
          f16x8 hcB = *(const f16x8*)&hc_st[swz(colv, (12 + ks) * 32 + l4 * 8)];
#pragma unroll
          for (int mt = 0; mt < 4; ++mt)
            a2[mt] = MFMA16(*(const f16x8*)(cbml_lds +
                (((ks * 16 + w * 4 + mt) << 6) + lane) * 8), hcB, a2[mt]);
        }
#pragma unroll
        for (int mt = 0; mt < 4; ++mt) {
          f16x4 v;
#pragma unroll
          for (int r = 0; r < 4; ++r) v[r] = (f16)(a2[mt][r] + mb[mt][r]);  // biased
          *(f16x4*)&m_st[colv * 264 + m2off + mt * 16] = v;
        }
        lbar();  // B2: mu|lv ready
        {
          f16x8 mu8 = *(const f16x8*)&m_st[be * 264 + d0];
          f16x8 lv8 = *(const f16x8*)&m_st[be * 264 + 128 + d0];
          float epv[8] = {ep0.x, ep0.y, ep0.z, ep0.w, ep1.x, ep1.y, ep1.z, ep1.w};
          f16x8 z8;
#pragma unroll
          for (int r = 0; r < 8; ++r) {
            float mu = (float)mu8[r], lv = (float)lv8[r];
            z8[r] = (f16)(mu + epv[r] * __builtin_amdgcn_exp2f(lv * 0.7213475204f));
          }
          *(f16x8*)&z_st[swz128(be, d0)] = z8;
          size_t o = ((size_t)t * BATCH + b0 + be) * ZDIM + d0;
          *(f16x8*)(z_all + o + (size_t)BATCH * ZDIM) = z8;  // slot t+1
          *(f16x8*)(mu_all + o) = mu8;
          *(f16x8*)(lv_all + o) = lv8;
        }
        lbar();  // B3: z_st/m_st safe
        ep0 = epn0; ep1 = epn1;
      }
    }
  }
}

// =====================================================================
// Phase D: parallel transition/emitter/losses over all (t,b).
// =====================================================================
__global__ __launch_bounds__(256) void dpar_kernel(
    const f16* __restrict__ z_all, const f16* __restrict__ mu_all,
    const f16* __restrict__ lv_all, const float* __restrict__ y,
    const float* __restrict__ eps_emit, const f16* __restrict__ pk,
    const float* __restrict__ g1b, const float* __restrict__ g2b,
    const float* __restrict__ p1b, const float* __restrict__ p2b,
    const float* __restrict__ tmub, const float* __restrict__ tlvb,
    const float* __restrict__ e1b, const float* __restrict__ e2b,
    const float* __restrict__ emub, const float* __restrict__ em_logvar,
    float* __restrict__ partials) {
  __shared__ __align__(16) f16 sb256[4][16 * 264];
  __shared__ __align__(16) f16 sb128[4][16 * 136];
  __shared__ float wsum[4][2];
  const int tid = threadIdx.x, lane = tid & 63, w = tid >> 6;
  const int colv = lane & 15, rb = (lane >> 4) << 2;
  const int m0 = blockIdx.x * 64 + w * 16;
  const int t = m0 >> 8, b0 = m0 & 255;
  f16* B256 = &sb256[w][0];
  f16* B128 = &sb128[w][0];

  f16x8 zp[4], zt[4];
  const f16* zpr = z_all + ((size_t)t * BATCH + b0) * ZDIM;
#pragma unroll
  for (int ks = 0; ks < 4; ++ks) {
    zp[ks] = *(const f16x8*)(zpr + (size_t)colv * ZDIM + ks * 32 + ((lane >> 4) << 3));
    zt[ks] = *(const f16x8*)(zpr + (size_t)BATCH * ZDIM + (size_t)colv * ZDIM + ks * 32 + ((lane >> 4) << 3));
  }

  f32x4 a16[16], a8[8];
  f16x8 af[8], af4[4];
  zacc<16>(a16); gemm_regA<4, 16>(zp, pk + PK_G1, lane, a16);
  store_relu<16>(a16, g1b, B256, 264, lane); ldsfence();
  load_af<8>(B256, 264, lane, af); ldsfence();
  zacc<8>(a8); gemm_regA<8, 8>(af, pk + PK_G2, lane, a8);
  f32x4 gate[8];
#pragma unroll
  for (int j = 0; j < 8; ++j)
#pragma unroll
    for (int r = 0; r < 4; ++r)
      gate[j][r] = 1.f / (1.f + expf(-(a8[j][r] + g2b[j * 16 + colv])));
  zacc<16>(a16); gemm_regA<4, 16>(zp, pk + PK_P1, lane, a16);
  store_relu<16>(a16, p1b, B256, 264, lane); ldsfence();
  load_af<8>(B256, 264, lane, af); ldsfence();
  zacc<8>(a8); gemm_regA<8, 8>(af, pk + PK_P2, lane, a8);
  f32x4 prop[8];
#pragma unroll
  for (int j = 0; j < 8; ++j)
#pragma unroll
    for (int r = 0; r < 4; ++r) {
      float v = a8[j][r] + p2b[j * 16 + colv];
      prop[j][r] = v;
      B128[(rb + r) * 136 + j * 16 + colv] = (f16)fmaxf(v, 0.f);
    }
  ldsfence();
  zacc<8>(a8); gemm_regA<4, 8>(zp, pk + PK_TMU, lane, a8);
  f32x4 prmu[8];
#pragma unroll
  for (int j = 0; j < 8; ++j)
#pragma unroll
    for (int r = 0; r < 4; ++r) {
      float gg = gate[j][r];
      prmu[j][r] = (1.f - gg) * (a8[j][r] + tmub[j * 16 + colv]) + gg * prop[j][r];
    }
  load_af<4>(B128, 136, lane, af4); ldsfence();
  zacc<8>(a8); gemm_regA<4, 8>(af4, pk + PK_TLV, lane, a8);
  f32x4 prlv[8];
#pragma unroll
  for (int j = 0; j < 8; ++j)
#pragma unroll
    for (int r = 0; r < 4; ++r) prlv[j][r] = a8[j][r] + tlvb[j * 16 + colv];
  zacc<16>(a16); gemm_regA<4, 16>(zt, pk + PK_E1, lane, a16);
  store_relu<16>(a16, e1b, B256, 264, lane); ldsfence();
  load_af<8>(B256, 264, lane, af); ldsfence();
  zacc<16>(a16); gemm_regA<8, 16>(af, pk + PK_E2, lane, a16);
  store_relu<16>(a16, e2b, B256, 264, lane); ldsfence();
  load_af<8>(B256, 264, lane, af); ldsfence();
  zacc<8>(a8); gemm_regA<8, 8>(af, pk + PK_EMU, lane, a8);
  float srec = 0.f, skl = 0.f;
#pragma unroll
  for (int j = 0; j < 8; ++j)
#pragma unroll
    for (int r = 0; r < 4; ++r) {
      int row = rb + r, n = j * 16 + colv;
      size_t tb = (size_t)t * BATCH + b0 + row;
      float xt = a8[j][r] + emub[n] + eps_emit[tb * DIMX + n] * expf(0.5f * em_logvar[n]);
      float dy = xt - y[((size_t)(b0 + row) * T_LEN + t) * DIMX + n];
      srec += dy * dy;
      float m_ = (float)mu_all[tb * ZDIM + n], l_ = (float)lv_all[tb * ZDIM + n];
      float dm = m_ - prmu[j][r];
      skl += 0.5f * (prlv[j][r] - l_ + (expf(l_) + dm * dm) * expf(-prlv[j][r]) - 1.f);
    }
#pragma unroll
  for (int off = 32; off; off >>= 1) {
    srec += __shfl_xor(srec, off);
    skl += __shfl_xor(skl, off);
  }
  if (lane == 0) { wsum[w][0] = srec; wsum[w][1] = skl; }
  __syncthreads();
  if (tid == 0) {
    partials[blockIdx.x * 2 + 0] = wsum[0][0] + wsum[1][0] + wsum[2][0] + wsum[3][0];
    partials[blockIdx.x * 2 + 1] = wsum[0][1] + wsum[1][1] + wsum[2][1] + wsum[3][1];
  }
}

// =====================================================================
__global__ void finalize_kernel(const float* __restrict__ partials, float* __restrict__ out) {
  __shared__ float sm[256][2];
  int tid = threadIdx.x;
  float r = 0.f, kk = 0.f;
  for (int i = tid; i < 2048; i += 256) {
    r += partials[2 * i];
    kk += partials[2 * i + 1];
  }
  sm[tid][0] = r; sm[tid][1] = kk;
  __syncthreads();
  for (int off = 128; off; off >>= 1) {
    if (tid < off) { sm[tid][0] += sm[tid + off][0]; sm[tid][1] += sm[tid + off][1]; }
    __syncthreads();
  }
  if (tid == 0) {
    out[0] = sm[0][0] / (131072.f * 128.f);
    out[1] = sm[0][1] / 131072.f;
  }
}

// =====================================================================
extern "C" void kernel_launch(void* const* d_in, const int* in_sizes, int n_in,
                              void* d_out, int out_size, void* d_ws, size_t ws_size,
                              hipStream_t stream) {
  (void)in_sizes; (void)n_in; (void)out_size;
  const float* x        = (const float*)d_in[0];
  const float* y        = (const float*)d_in[1];
  const float* eps_comb = (const float*)d_in[2];
  const float* eps_emit = (const float*)d_in[3];
  const float* wih = (const float*)d_in[4];
  const float* whh = (const float*)d_in[5];
  const float* bih = (const float*)d_in[6];
  const float* bhh = (const float*)d_in[7];
  const float* h0  = (const float*)d_in[8];
  const float* zq0 = (const float*)d_in[9];
  const float* g1W = (const float*)d_in[10]; const float* g1b = (const float*)d_in[11];
  const float* g2W = (const float*)d_in[12]; const float* g2b = (const float*)d_in[13];
  const float* p1W = (const float*)d_in[14]; const float* p1b = (const float*)d_in[15];
  const float* p2W = (const float*)d_in[16]; const float* p2b = (const float*)d_in[17];
  const float* tmuW = (const float*)d_in[18]; const float* tmub = (const float*)d_in[19];
  const float* tlvW = (const float*)d_in[20]; const float* tlvb = (const float*)d_in[21];
  const float* chW = (const float*)d_in[22]; const float* chb = (const float*)d_in[23];
  const float* cmW = (const float*)d_in[24]; const float* cmb = (const float*)d_in[25];
  const float* clW = (const float*)d_in[26]; const float* clb = (const float*)d_in[27];
  const float* e1W = (const float*)d_in[28]; const float* e1b = (const float*)d_in[29];
  const float* e2W = (const float*)d_in[30]; const float* e2b = (const float*)d_in[31];
  const float* emW = (const float*)d_in[32]; const float* emb = (const float*)d_in[33];
  const float* elv = (const float*)d_in[34];

  char* ws = (char*)d_ws;
  f16*  xw      = (f16*)(ws + WS_XW);
  f16*  z_all   = (f16*)(ws + WS_Z);
  f16*  mu_all  = (f16*)(ws + WS_MU);
  f16*  lv_all  = (f16*)(ws + WS_LV);
  f16*  pk      = (f16*)(ws + WS_PK);
  float* partials = (float*)(ws + WS_PART);
  unsigned* prog  = (unsigned*)(ws + WS_PROG);
  float* out = (float*)d_out;
  if (ws_size < WS_END) return;

  zero_prog_kernel<<<dim3(1), dim3(64), 0, stream>>>(prog);

  PackTab tb;
  unsigned wg = 0; int ei = 0;
#define PACK(S1, S2, NS_, K_, N_, OFF) \
  tb.e[ei] = PackEnt{S1, S2, NS_, K_, N_, OFF, wg}; wg += (unsigned)((K_) * (N_)) / 256; ++ei;
  PACK(wih, wih, 512, 128, 512, PK_WIH);
  PACK(whh, whh, 512, 512, 512, PK_WHH);
  PACK(g1W, g1W, 256, 128, 256, PK_G1);
  PACK(g2W, g2W, 128, 256, 128, PK_G2);
  PACK(p1W, p1W, 256, 128, 256, PK_P1);
  PACK(p2W, p2W, 128, 256, 128, PK_P2);
  PACK(tmuW, tmuW, 128, 128, 128, PK_TMU);
  PACK(tlvW, tlvW, 128, 128, 128, PK_TLV);
  PACK(chW, chW, 512, 128, 512, PK_CBH);
  PACK(cmW, clW, 128, 512, 256, PK_CBML);
  PACK(e1W, e1W, 256, 128, 256, PK_E1);
  PACK(e2W, e2W, 256, 256, 256, PK_E2);
  PACK(emW, emW, 128, 256, 128, PK_EMU);
#undef PACK
  pack_all_kernel<<<dim3(wg), dim3(256), 0, stream>>>(tb, pk);

  xw_kernel<<<dim3(2048), dim3(256), 0, stream>>>(x, pk, bih, bhh, xw);
  scan_pipe_kernel<<<dim3(32), dim3(256), 0, stream>>>(
      pk, h0, zq0, chb, cmb, clb, eps_comb, xw, z_all, mu_all, lv_all, prog);
  dpar_kernel<<<dim3(2048), dim3(256), 0, stream>>>(z_all, mu_all, lv_all, y, eps_emit, pk,
                                                    g1b, g2b, p1b, p2b, tmub, tlvb, e1b, e2b,
                                                    emb, elv, partials);
  finalize_kernel<<<dim3(1), dim3(256), 0, stream>>>(partials, out);
}